// Round 11
// baseline (1742.491 us; speedup 1.0000x reference)
//
#include <hip/hip_runtime.h>

#define NLAYERS 6
#define BSZ 16
#define NQL 300
#define DM 256
#define NHEAD 8
#define HDIM 32
#define NLVL 3
#define NPT 4
#define DFFN 1024
#define NCLS 80
#define LVTOT 8400
#define NROW (BSZ * NQL)   // 4800
#define MEMN (BSZ * LVTOT) // 134400

typedef __attribute__((ext_vector_type(8))) short bf16x8;
typedef __attribute__((ext_vector_type(8))) ushort us8;
typedef __attribute__((ext_vector_type(4))) float f32x4;

__device__ __forceinline__ float b2f(ushort u) {
    return __uint_as_float(((uint)u) << 16);
}
__device__ __forceinline__ ushort f2b(float f) {
    uint i = __float_as_uint(f);
    uint r = i + 0x7fffu + ((i >> 16) & 1u);   // RNE
    return (ushort)(r >> 16);
}
__device__ __forceinline__ void split2(float v, ushort& h, ushort& l) {
    ushort hh = f2b(v);
    h = hh;
    l = f2b(v - b2f(hh));
}
// async global -> LDS, 16 bytes per lane (LDS dest = wave base + lane*16)
__device__ __forceinline__ void gl_lds16(const void* g, void* l) {
    __builtin_amdgcn_global_load_lds(
        (const __attribute__((address_space(1))) unsigned int*)g,
        (__attribute__((address_space(3))) unsigned int*)l, 16, 0, 0);
}

// ---------------------------------------------------------------------------
// fp32 -> bf16 plane (4 elems/thread)
// ---------------------------------------------------------------------------
__global__ __launch_bounds__(256) void f2b_kernel(
    const float* __restrict__ src, ushort* __restrict__ dst, int n)
{
    int i = (blockIdx.x * 256 + threadIdx.x) * 4;
    if (i < n) {
        float4 v = *(const float4*)&src[i];
        ushort4 o = {f2b(v.x), f2b(v.y), f2b(v.z), f2b(v.w)};
        *(ushort4*)&dst[i] = o;
    }
}

// fp32 -> bf16 hi + lo planes (4 elems/thread)
__global__ __launch_bounds__(256) void split_kernel(
    const float* __restrict__ src, ushort* __restrict__ dh,
    ushort* __restrict__ dl, int n)
{
    int i = (blockIdx.x * 256 + threadIdx.x) * 4;
    if (i < n) {
        float4 v = *(const float4*)&src[i];
        ushort4 h, l;
        split2(v.x, h.x, l.x);
        split2(v.y, h.y, l.y);
        split2(v.z, h.z, l.z);
        split2(v.w, h.w, l.w);
        *(ushort4*)&dh[i] = h;
        *(ushort4*)&dl[i] = l;
    }
}

// ---------------------------------------------------------------------------
// Batched transpose + bf16-hi: one dispatch for all weight preprocessing.
// ---------------------------------------------------------------------------
#define NTE 14
struct TTab {
    const float* s[NTE];
    ushort* d[NTE];
    int K[NTE], N[NTE], dls[NTE], dr0[NTE];
    int tstart[NTE + 1];
};

__global__ __launch_bounds__(256) void transpose_batch_kernel(TTab tab)
{
    __shared__ float tile[32][33];
    const int bx = blockIdx.x;
    int e = 0;
    while (e < NTE - 1 && bx >= tab.tstart[e + 1]) ++e;
    const int local = bx - tab.tstart[e];
    const int K = tab.K[e], N = tab.N[e];
    const int tx_n = (N + 31) >> 5, ty_n = (K + 31) >> 5;
    const int perB = tx_n * ty_n;
    const int z = local / perB;
    const int rem = local - z * perB;
    const int tyi = rem / tx_n, txi = rem - tyi * tx_n;
    const float* src = tab.s[e] + (size_t)z * K * N;
    ushort* dh = tab.d[e] + (size_t)z * tab.dls[e] + (size_t)tab.dr0[e] * K;
    const int n0 = txi * 32, k0 = tyi * 32;
    const int tx = threadIdx.x, ty = threadIdx.y;   // 32 x 8
    for (int r = 0; r < 32; r += 8) {
        int k = k0 + ty + r, n = n0 + tx;
        if (k < K && n < N) tile[ty + r][tx] = src[(size_t)k * N + n];
    }
    __syncthreads();
    for (int r = 0; r < 32; r += 8) {
        int n = n0 + ty + r, k = k0 + tx;
        if (n < N && k < K) dh[(size_t)n * K + k] = f2b(tile[tx][ty + r]);
    }
}

// ---------------------------------------------------------------------------
// Both bias concats in one dispatch (12 + 7 blocks)
// ---------------------------------------------------------------------------
__global__ __launch_bounds__(256) void concat_both_kernel(
    const float* __restrict__ bq, const float* __restrict__ bk, float* __restrict__ bqk,
    const float* __restrict__ boff, const float* __restrict__ baw, float* __restrict__ bfa)
{
    const int bx = blockIdx.x;
    if (bx < 12) {
        int i = bx * 256 + threadIdx.x;
        if (i < 6 * 512) {
            int l = i / 512, j = i - l * 512;
            bqk[i] = (j < 256) ? bq[l * 256 + j] : bk[l * 256 + j - 256];
        }
    } else {
        int i = (bx - 12) * 256 + threadIdx.x;
        if (i < 6 * 288) {
            int l = i / 288, j = i - l * 288;
            bfa[i] = (j < 192) ? boff[l * 192 + j] : baw[l * 96 + j - 192];
        }
    }
}

// ---------------------------------------------------------------------------
// Pre-split-A MFMA GEMM (64x64 tile, double-buffered, fully async staging).
// ---------------------------------------------------------------------------
template <int ACT>
__global__ __launch_bounds__(256) void gemm_ps(
    const ushort* __restrict__ Ahp, const ushort* __restrict__ Alp,
    const ushort* __restrict__ BTh, const float* __restrict__ bias,
    int M, int N, int K,
    float* __restrict__ Cf, const float* __restrict__ addsrc,
    ushort* __restrict__ Ch, ushort* __restrict__ Cl)
{
    __shared__ __align__(16) ushort Ahs[2][64 * 32];
    __shared__ __align__(16) ushort Als[2][64 * 32];
    __shared__ __align__(16) ushort Bhs[2][64 * 32];

    const int tid  = threadIdx.x;
    const int m0   = blockIdx.x * 64;
    const int n0   = blockIdx.y * 64;
    const int wv   = tid >> 6;
    const int lane = tid & 63;
    const int lm   = lane & 15;
    const int lq   = lane >> 4;
    const int r    = tid >> 2;
    const int c8   = (tid & 3) * 8;

    gl_lds16(&Ahp[(size_t)(m0 + r) * K + c8], &Ahs[0][r * 32 + c8]);
    gl_lds16(&Alp[(size_t)(m0 + r) * K + c8], &Als[0][r * 32 + c8]);
    gl_lds16(&BTh[(size_t)(n0 + r) * K + c8], &Bhs[0][r * 32 + c8]);
    __syncthreads();

    f32x4 acc[4] = {};
    int buf = 0;
    for (int k0 = 32; k0 < K + 32; k0 += 32) {
        const int nxt = buf ^ 1;
        if (k0 < K) {
            gl_lds16(&Ahp[(size_t)(m0 + r) * K + k0 + c8], &Ahs[nxt][r * 32 + c8]);
            gl_lds16(&Alp[(size_t)(m0 + r) * K + k0 + c8], &Als[nxt][r * 32 + c8]);
            gl_lds16(&BTh[(size_t)(n0 + r) * K + k0 + c8], &Bhs[nxt][r * 32 + c8]);
        }
        bf16x8 afh = *(const bf16x8*)&Ahs[buf][(wv * 16 + lm) * 32 + lq * 8];
        bf16x8 afl = *(const bf16x8*)&Als[buf][(wv * 16 + lm) * 32 + lq * 8];
#pragma unroll
        for (int nb = 0; nb < 4; ++nb) {
            bf16x8 bfh = *(const bf16x8*)&Bhs[buf][(nb * 16 + lm) * 32 + lq * 8];
            acc[nb] = __builtin_amdgcn_mfma_f32_16x16x32_bf16(afh, bfh, acc[nb], 0, 0, 0);
            acc[nb] = __builtin_amdgcn_mfma_f32_16x16x32_bf16(afl, bfh, acc[nb], 0, 0, 0);
        }
        __syncthreads();
        buf = nxt;
    }

    const int row = m0 + wv * 16 + lq * 4;
#pragma unroll
    for (int nb = 0; nb < 4; ++nb) {
        int col = n0 + nb * 16 + lm;
        if (col < N) {
            float bv = bias ? bias[col] : 0.f;
#pragma unroll
            for (int rr = 0; rr < 4; ++rr) {
                float v = acc[nb][rr] + bv;
                if (ACT) v = fmaxf(v, 0.f);
                const size_t idx = (size_t)(row + rr) * N + col;
                if (Cf) Cf[idx] = v;
                if (Ch) {
                    float w = addsrc ? (v + addsrc[idx]) : v;
                    ushort h, l;
                    split2(w, h, l);
                    Ch[idx] = h;
                    if (Cl) Cl[idx] = l;
                }
            }
        }
    }
}

// ---------------------------------------------------------------------------
// Tiny-tile pre-split GEMM (16x64, double-buffered). Grid (M/16, N/64) ->
// ~4.7 waves/SIMD at the low-occupancy call sites.
// ---------------------------------------------------------------------------
template <int ACT>
__global__ __launch_bounds__(256) void gemm_ps16(
    const ushort* __restrict__ Ahp, const ushort* __restrict__ Alp,
    const ushort* __restrict__ BTh, const float* __restrict__ bias,
    int M, int N, int K,
    float* __restrict__ Cf, const float* __restrict__ addsrc,
    ushort* __restrict__ Ch, ushort* __restrict__ Cl)
{
    __shared__ __align__(16) ushort Ahs[2][16 * 32];
    __shared__ __align__(16) ushort Als[2][16 * 32];
    __shared__ __align__(16) ushort Bhs[2][64 * 32];

    const int tid  = threadIdx.x;
    const int m0   = blockIdx.x * 16;
    const int n0   = blockIdx.y * 64;
    const int wv   = tid >> 6;
    const int lane = tid & 63;
    const int lm   = lane & 15;
    const int lq   = lane >> 4;
    const int ra   = (tid & 63) >> 2;    // 0..15 (A rows; tid<64 -> Ah, tid<128 -> Al)
    const int rb   = tid >> 2;           // 0..63 (B rows)
    const int c8   = (tid & 3) * 8;

    if (tid < 64)        gl_lds16(&Ahp[(size_t)(m0 + ra) * K + c8], &Ahs[0][ra * 32 + c8]);
    else if (tid < 128)  gl_lds16(&Alp[(size_t)(m0 + ra) * K + c8], &Als[0][ra * 32 + c8]);
    gl_lds16(&BTh[(size_t)(n0 + rb) * K + c8], &Bhs[0][rb * 32 + c8]);
    __syncthreads();

    f32x4 acc = {};
    int buf = 0;
    for (int k0 = 32; k0 < K + 32; k0 += 32) {
        const int nxt = buf ^ 1;
        if (k0 < K) {
            if (tid < 64)       gl_lds16(&Ahp[(size_t)(m0 + ra) * K + k0 + c8], &Ahs[nxt][ra * 32 + c8]);
            else if (tid < 128) gl_lds16(&Alp[(size_t)(m0 + ra) * K + k0 + c8], &Als[nxt][ra * 32 + c8]);
            gl_lds16(&BTh[(size_t)(n0 + rb) * K + k0 + c8], &Bhs[nxt][rb * 32 + c8]);
        }
        bf16x8 bfh = *(const bf16x8*)&Bhs[buf][(wv * 16 + lm) * 32 + lq * 8];
        bf16x8 afh = *(const bf16x8*)&Ahs[buf][lm * 32 + lq * 8];
        bf16x8 afl = *(const bf16x8*)&Als[buf][lm * 32 + lq * 8];
        acc = __builtin_amdgcn_mfma_f32_16x16x32_bf16(afh, bfh, acc, 0, 0, 0);
        acc = __builtin_amdgcn_mfma_f32_16x16x32_bf16(afl, bfh, acc, 0, 0, 0);
        __syncthreads();
        buf = nxt;
    }

    const int col = n0 + wv * 16 + lm;
    if (col < N) {
        const float bv = bias ? bias[col] : 0.f;
        const int row = m0 + lq * 4;
#pragma unroll
        for (int rr = 0; rr < 4; ++rr) {
            float v = acc[rr] + bv;
            if (ACT) v = fmaxf(v, 0.f);
            const size_t idx = (size_t)(row + rr) * N + col;
            if (Cf) Cf[idx] = v;
            if (Ch) {
                float w = addsrc ? (v + addsrc[idx]) : v;
                ushort h, l;
                split2(w, h, l);
                Ch[idx] = h;
                if (Cl) Cl[idx] = l;
            }
        }
    }
}

// ---------------------------------------------------------------------------
// Mixed dispatch: small 64x64 GEMM (no act) + chunk of the 128x128 val-proj
// GEMM (M=MEMN, N=256, K=256). Big path now DOUBLE-BUFFERED (stage k+1
// overlaps compute k) — same MFMA order, bit-identical results.
// LDS: 32 KB union (small path 24 KB, big path 2x(8+8) KB).
// ---------------------------------------------------------------------------
__global__ __launch_bounds__(256) void gemm_mix(
    const ushort* __restrict__ Ahp, const ushort* __restrict__ Alp,
    const ushort* __restrict__ BTh, const float* __restrict__ bias,
    int N, int K,
    float* __restrict__ Cf, const float* __restrict__ addsrc,
    ushort* __restrict__ Ch, ushort* __restrict__ Cl,
    int nSmall,
    const ushort* __restrict__ gA, const ushort* __restrict__ gB,
    const float* __restrict__ gbias, ushort* __restrict__ gC,
    int chunkOff)
{
    __shared__ __align__(16) ushort lds[16384];   // 32 KB

    const int tid  = threadIdx.x;
    const int wv   = tid >> 6;
    const int lane = tid & 63;
    const int lm   = lane & 15;
    const int lq   = lane >> 4;

    if ((int)blockIdx.x < nSmall) {
        typedef ushort (*lds2)[64 * 32];
        lds2 Ahs = (lds2)lds;
        lds2 Als = (lds2)(lds + 4096);
        lds2 Bhs = (lds2)(lds + 8192);
        const int m0 = (blockIdx.x % 75) * 64;
        const int n0 = (blockIdx.x / 75) * 64;
        const int r  = tid >> 2;
        const int c8 = (tid & 3) * 8;

        gl_lds16(&Ahp[(size_t)(m0 + r) * K + c8], &Ahs[0][r * 32 + c8]);
        gl_lds16(&Alp[(size_t)(m0 + r) * K + c8], &Als[0][r * 32 + c8]);
        gl_lds16(&BTh[(size_t)(n0 + r) * K + c8], &Bhs[0][r * 32 + c8]);
        __syncthreads();

        f32x4 acc[4] = {};
        int buf = 0;
        for (int k0 = 32; k0 < K + 32; k0 += 32) {
            const int nxt = buf ^ 1;
            if (k0 < K) {
                gl_lds16(&Ahp[(size_t)(m0 + r) * K + k0 + c8], &Ahs[nxt][r * 32 + c8]);
                gl_lds16(&Alp[(size_t)(m0 + r) * K + k0 + c8], &Als[nxt][r * 32 + c8]);
                gl_lds16(&BTh[(size_t)(n0 + r) * K + k0 + c8], &Bhs[nxt][r * 32 + c8]);
            }
            bf16x8 afh = *(const bf16x8*)&Ahs[buf][(wv * 16 + lm) * 32 + lq * 8];
            bf16x8 afl = *(const bf16x8*)&Als[buf][(wv * 16 + lm) * 32 + lq * 8];
#pragma unroll
            for (int nb = 0; nb < 4; ++nb) {
                bf16x8 bfh = *(const bf16x8*)&Bhs[buf][(nb * 16 + lm) * 32 + lq * 8];
                acc[nb] = __builtin_amdgcn_mfma_f32_16x16x32_bf16(afh, bfh, acc[nb], 0, 0, 0);
                acc[nb] = __builtin_amdgcn_mfma_f32_16x16x32_bf16(afl, bfh, acc[nb], 0, 0, 0);
            }
            __syncthreads();
            buf = nxt;
        }

        const int row = m0 + wv * 16 + lq * 4;
#pragma unroll
        for (int nb = 0; nb < 4; ++nb) {
            int col = n0 + nb * 16 + lm;
            if (col < N) {
                float bv = bias[col];
#pragma unroll
                for (int rr = 0; rr < 4; ++rr) {
                    float v = acc[nb][rr] + bv;
                    const size_t idx = (size_t)(row + rr) * N + col;
                    if (Cf) Cf[idx] = v;
                    if (Ch) {
                        float w = addsrc ? (v + addsrc[idx]) : v;
                        ushort h, l;
                        split2(w, h, l);
                        Ch[idx] = h;
                        if (Cl) Cl[idx] = l;
                    }
                }
            }
        }
    } else {
        // ---- 128x128 val-projection chunk, double-buffered ----
        ushort* As = lds;            // [2][128*32] = 2 x 4096 ushorts
        ushort* Bs = lds + 8192;     // [2][128*32]
        const int bid = (int)blockIdx.x - nSmall + chunkOff;
        const int n0 = (bid & 1) * 128;
        const int m0 = (bid >> 1) * 128;
        const int wr = wv >> 1, wc = wv & 1;
        const int srow = lane >> 2;
        const int scol = (lane & 3) * 8;

        // prologue: stage tile 0
#pragma unroll
        for (int s2 = 0; s2 < 2; ++s2) {
            const int seg = wv * 2 + s2;
            const int row = seg * 16 + srow;
            gl_lds16(&gA[(size_t)(m0 + row) * 256 + scol], &As[seg * 512 + lane * 8]);
            gl_lds16(&gB[(size_t)(n0 + row) * 256 + scol], &Bs[seg * 512 + lane * 8]);
        }
        __syncthreads();

        f32x4 acc[4][4] = {};
        int buf = 0;
        for (int k0 = 32; k0 < 256 + 32; k0 += 32) {
            const int nxt = buf ^ 1;
            if (k0 < 256) {
#pragma unroll
                for (int s2 = 0; s2 < 2; ++s2) {
                    const int seg = wv * 2 + s2;
                    const int row = seg * 16 + srow;
                    gl_lds16(&gA[(size_t)(m0 + row) * 256 + k0 + scol],
                             &As[nxt * 4096 + seg * 512 + lane * 8]);
                    gl_lds16(&gB[(size_t)(n0 + row) * 256 + k0 + scol],
                             &Bs[nxt * 4096 + seg * 512 + lane * 8]);
                }
            }
            bf16x8 af[4], bfr[4];
#pragma unroll
            for (int i = 0; i < 4; ++i)
                af[i] = *(const bf16x8*)&As[buf * 4096 + (wr * 64 + i * 16 + lm) * 32 + lq * 8];
#pragma unroll
            for (int i = 0; i < 4; ++i)
                bfr[i] = *(const bf16x8*)&Bs[buf * 4096 + (wc * 64 + i * 16 + lm) * 32 + lq * 8];
#pragma unroll
            for (int mi = 0; mi < 4; ++mi)
#pragma unroll
                for (int ni = 0; ni < 4; ++ni)
                    acc[mi][ni] = __builtin_amdgcn_mfma_f32_16x16x32_bf16(
                        af[mi], bfr[ni], acc[mi][ni], 0, 0, 0);
            __syncthreads();
            buf = nxt;
        }

#pragma unroll
        for (int ni = 0; ni < 4; ++ni) {
            const int col = n0 + wc * 64 + ni * 16 + lm;
            const float bv = gbias[col];
#pragma unroll
            for (int mi = 0; mi < 4; ++mi) {
                const int row = m0 + wr * 64 + mi * 16 + lq * 4;
#pragma unroll
                for (int rr = 0; rr < 4; ++rr)
                    gC[(size_t)(row + rr) * 256 + col] = f2b(acc[mi][ni][rr] + bv);
            }
        }
    }
}

// ---------------------------------------------------------------------------
// Merged QK + V projection GEMM: one dispatch, grid (75, 12).
// ---------------------------------------------------------------------------
__global__ __launch_bounds__(256) void gemm_qkv(
    const ushort* __restrict__ qhp, const ushort* __restrict__ qlp,
    const ushort* __restrict__ ohp, const ushort* __restrict__ olp,
    const ushort* __restrict__ Bqk, const ushort* __restrict__ Bv,
    const float* __restrict__ biasqk, const float* __restrict__ biasv,
    ushort* __restrict__ Cqk, ushort* __restrict__ Cv)
{
    constexpr int K = 256;
    __shared__ __align__(16) ushort Ahs[2][64 * 32];
    __shared__ __align__(16) ushort Als[2][64 * 32];
    __shared__ __align__(16) ushort Bhs[2][64 * 32];

    const int by = blockIdx.y;
    const ushort *Ahp, *Alp, *BTh;
    const float* bias;
    ushort* Ch;
    int N, n0;
    if (by < 8) { Ahp = qhp; Alp = qlp; BTh = Bqk; bias = biasqk; Ch = Cqk; N = 512; n0 = by * 64; }
    else        { Ahp = ohp; Alp = olp; BTh = Bv;  bias = biasv;  Ch = Cv;  N = 256; n0 = (by - 8) * 64; }

    const int tid  = threadIdx.x;
    const int m0   = blockIdx.x * 64;
    const int wv   = tid >> 6;
    const int lane = tid & 63;
    const int lm   = lane & 15;
    const int lq   = lane >> 4;
    const int r    = tid >> 2;
    const int c8   = (tid & 3) * 8;

    gl_lds16(&Ahp[(size_t)(m0 + r) * K + c8], &Ahs[0][r * 32 + c8]);
    gl_lds16(&Alp[(size_t)(m0 + r) * K + c8], &Als[0][r * 32 + c8]);
    gl_lds16(&BTh[(size_t)(n0 + r) * K + c8], &Bhs[0][r * 32 + c8]);
    __syncthreads();

    f32x4 acc[4] = {};
    int buf = 0;
    for (int k0 = 32; k0 < K + 32; k0 += 32) {
        const int nxt = buf ^ 1;
        if (k0 < K) {
            gl_lds16(&Ahp[(size_t)(m0 + r) * K + k0 + c8], &Ahs[nxt][r * 32 + c8]);
            gl_lds16(&Alp[(size_t)(m0 + r) * K + k0 + c8], &Als[nxt][r * 32 + c8]);
            gl_lds16(&BTh[(size_t)(n0 + r) * K + k0 + c8], &Bhs[nxt][r * 32 + c8]);
        }
        bf16x8 afh = *(const bf16x8*)&Ahs[buf][(wv * 16 + lm) * 32 + lq * 8];
        bf16x8 afl = *(const bf16x8*)&Als[buf][(wv * 16 + lm) * 32 + lq * 8];
#pragma unroll
        for (int nb = 0; nb < 4; ++nb) {
            bf16x8 bfh = *(const bf16x8*)&Bhs[buf][(nb * 16 + lm) * 32 + lq * 8];
            acc[nb] = __builtin_amdgcn_mfma_f32_16x16x32_bf16(afh, bfh, acc[nb], 0, 0, 0);
            acc[nb] = __builtin_amdgcn_mfma_f32_16x16x32_bf16(afl, bfh, acc[nb], 0, 0, 0);
        }
        __syncthreads();
        buf = nxt;
    }

    const int row = m0 + wv * 16 + lq * 4;
#pragma unroll
    for (int nb = 0; nb < 4; ++nb) {
        const int col = n0 + nb * 16 + lm;
        const float bv = bias[col];
#pragma unroll
        for (int rr = 0; rr < 4; ++rr)
            Ch[(size_t)(row + rr) * N + col] = f2b(acc[nb][rr] + bv);
    }
}

// ---------------------------------------------------------------------------
// MFMA MHA: one block per (b, h, q-QUARTER); grid 512 = 2 blocks/CU.
// ---------------------------------------------------------------------------
__global__ __launch_bounds__(256) void mha_mfma_kernel(
    const ushort* __restrict__ qh, int ldq, const ushort* __restrict__ kh, int ldk,
    const ushort* __restrict__ vh, int ldv,
    ushort* __restrict__ outh, ushort* __restrict__ outl)
{
    __shared__ ushort Kh[304 * 36];
    __shared__ ushort Vth[32 * 328];
    __shared__ ushort Pb[4][16 * 168];

    const int tid = threadIdx.x;
    const int wv = tid >> 6, lane = tid & 63;
    const int bh = blockIdx.x >> 2, quarter = blockIdx.x & 3;
    const int b = bh >> 3, h = bh & 7;
    const size_t qbase = (size_t)b * NQL * ldq + h * HDIM;
    const size_t kbase = (size_t)b * NQL * ldk + h * HDIM;
    const size_t vbase = (size_t)b * NQL * ldv + h * HDIM;
    const size_t obase = (size_t)b * NQL * DM + h * HDIM;

    for (int idx = tid; idx < 304 * 4; idx += 256) {
        const int row = idx >> 2, d0 = (idx & 3) * 8;
        us8 v = {};
        if (row < NQL) v = *(const us8*)&kh[kbase + (size_t)row * ldk + d0];
        ushort* o = &Kh[row * 36 + d0];
#pragma unroll
        for (int x = 0; x < 8; ++x) o[x] = v[x];
    }
    for (int idx = tid; idx < 328 * 4; idx += 256) {
        const int key = idx >> 2, d0 = (idx & 3) * 8;
        us8 v = {};
        if (key < NQL) v = *(const us8*)&vh[vbase + (size_t)key * ldv + d0];
#pragma unroll
        for (int x = 0; x < 8; ++x) Vth[(d0 + x) * 328 + key] = v[x];
    }
    for (int i = lane; i < 16 * 168; i += 64) Pb[wv][i] = 0;
    __syncthreads();

    const int quad = lane >> 4, c = lane & 15;
    const float scale = 0.17677669529663687f;

    const int qt_beg = quarter * 5 + wv;
    const int qt_end = min(quarter * 5 + 5, 19);
    for (int qt = qt_beg; qt < qt_end; qt += 4) {
        const int q = qt * 16 + c;
        bf16x8 qf = *(const bf16x8*)&qh[qbase + (size_t)q * ldq + quad * 8];

        f32x4 sc[19];
#pragma unroll
        for (int kt = 0; kt < 19; ++kt) {
            bf16x8 kf = *(const bf16x8*)&Kh[(kt * 16 + c) * 36 + quad * 8];
            f32x4 a = {};
            a = __builtin_amdgcn_mfma_f32_16x16x32_bf16(qf, kf, a, 0, 0, 0);
            sc[kt] = a;
        }
        float inv4[4];
#pragma unroll
        for (int r = 0; r < 4; ++r) {
            float mx = -1e30f;
#pragma unroll
            for (int kt = 0; kt < 19; ++kt) {
                float s = sc[kt][r] * scale;
                if (kt * 16 + c >= NQL) s = -1e30f;
                sc[kt][r] = s;
                mx = fmaxf(mx, s);
            }
#pragma unroll
            for (int m = 1; m < 16; m <<= 1) mx = fmaxf(mx, __shfl_xor(mx, m, 64));
            float l = 0.f;
#pragma unroll
            for (int kt = 0; kt < 19; ++kt) {
                float p = __expf(sc[kt][r] - mx);
                sc[kt][r] = p;
                l += p;
            }
#pragma unroll
            for (int m = 1; m < 16; m <<= 1) l += __shfl_xor(l, m, 64);
            inv4[r] = 1.f / l;
        }

        f32x4 o0 = {}, o1 = {};
#pragma unroll
        for (int r = 0; r < 4; ++r)
#pragma unroll
            for (int kt = 0; kt < 10; ++kt)
                Pb[wv][(quad * 4 + r) * 168 + kt * 16 + c] = f2b(sc[kt][r] * inv4[r]);
#pragma unroll
        for (int ks = 0; ks < 5; ++ks) {
            bf16x8 pf = *(const bf16x8*)&Pb[wv][c * 168 + ks * 32 + quad * 8];
            bf16x8 v0 = *(const bf16x8*)&Vth[c * 328 + ks * 32 + quad * 8];
            bf16x8 v1 = *(const bf16x8*)&Vth[(16 + c) * 328 + ks * 32 + quad * 8];
            o0 = __builtin_amdgcn_mfma_f32_16x16x32_bf16(pf, v0, o0, 0, 0, 0);
            o1 = __builtin_amdgcn_mfma_f32_16x16x32_bf16(pf, v1, o1, 0, 0, 0);
        }
#pragma unroll
        for (int r = 0; r < 4; ++r) {
#pragma unroll
            for (int kt = 10; kt < 19; ++kt)
                Pb[wv][(quad * 4 + r) * 168 + (kt - 10) * 16 + c] = f2b(sc[kt][r] * inv4[r]);
            Pb[wv][(quad * 4 + r) * 168 + 144 + c] = 0;
        }
#pragma unroll
        for (int ks = 0; ks < 5; ++ks) {
            bf16x8 pf = *(const bf16x8*)&Pb[wv][c * 168 + ks * 32 + quad * 8];
            bf16x8 v0 = *(const bf16x8*)&Vth[c * 328 + 160 + ks * 32 + quad * 8];
            bf16x8 v1 = *(const bf16x8*)&Vth[(16 + c) * 328 + 160 + ks * 32 + quad * 8];
            o0 = __builtin_amdgcn_mfma_f32_16x16x32_bf16(pf, v0, o0, 0, 0, 0);
            o1 = __builtin_amdgcn_mfma_f32_16x16x32_bf16(pf, v1, o1, 0, 0, 0);
        }
#pragma unroll
        for (int r = 0; r < 4; ++r) {
            const int qq = qt * 16 + quad * 4 + r;
            if (qq < NQL) {
                ushort hh, ll;
                split2(o0[r], hh, ll);
                outh[obase + (size_t)qq * DM + c] = hh;
                outl[obase + (size_t)qq * DM + c] = ll;
                split2(o1[r], hh, ll);
                outh[obase + (size_t)qq * DM + 16 + c] = hh;
                outl[obase + (size_t)qq * DM + 16 + c] = ll;
            }
        }
    }
}

// ---------------------------------------------------------------------------
// Deformable sampling — 4 rows/block (grid 1200), 4 adjacent d per thread
// via aligned uint2 loads. Per-element FP order identical.
// ---------------------------------------------------------------------------
__global__ __launch_bounds__(256) void deform_kernel(
    const ushort* __restrict__ val, const float* __restrict__ offaw,
    const float* __restrict__ refd,
    ushort* __restrict__ samph, ushort* __restrict__ sampl)
{
    __shared__ float offs[4][192];
    __shared__ float aws[4][96];
    __shared__ float rr4[4][4];
    const int row0 = blockIdx.x * 4;
    const int t = threadIdx.x;
    for (int i = t; i < 4 * 288; i += 256) {
        const int rh = i / 288, j = i - rh * 288;
        const float v = offaw[(size_t)(row0 + rh) * 288 + j];
        if (j < 192) offs[rh][j] = v;
        else         aws[rh][j - 192] = v;
    }
    if (t < 16) rr4[t >> 2][t & 3] = refd[(size_t)(row0 + (t >> 2)) * 4 + (t & 3)];
    __syncthreads();

    const int sub = t >> 6;              // row within the quad
    const int row = row0 + sub;
    const int b = row / NQL;
    const int t6 = t & 63;
    const int h = t6 >> 3;               // 0..7
    const int d4 = (t6 & 7) * 4;         // 0,4,..,28

    float mx = -1e30f;
#pragma unroll
    for (int j = 0; j < 12; ++j) mx = fmaxf(mx, aws[sub][h * 12 + j]);
    float ev[12]; float se = 0.f;
#pragma unroll
    for (int j = 0; j < 12; ++j) { ev[j] = __expf(aws[sub][h * 12 + j] - mx); se += ev[j]; }
    const float inv = 1.f / se;

    const float r0 = rr4[sub][0], r1 = rr4[sub][1];
    const float r2 = rr4[sub][2], r3 = rr4[sub][3];

    const int HWs[3] = {80, 40, 20};
    const int STs[3] = {0, 6400, 8000};
    float acc0 = 0.f, acc1 = 0.f, acc2 = 0.f, acc3 = 0.f;
#pragma unroll
    for (int l = 0; l < NLVL; ++l) {
        const int Wd = HWs[l], Hd = HWs[l], st = STs[l];
#pragma unroll
        for (int p = 0; p < NPT; ++p) {
            const float w12 = ev[l * 4 + p] * inv;
            const float ox = offs[sub][((h * 3 + l) * 4 + p) * 2 + 0];
            const float oy = offs[sub][((h * 3 + l) * 4 + p) * 2 + 1];
            const float x = (r0 + ox * 0.125f * r2) * Wd - 0.5f;
            const float y = (r1 + oy * 0.125f * r3) * Hd - 0.5f;
            const float xf = floorf(x), yf = floorf(y);
            const int x0 = (int)xf, y0 = (int)yf;
            const float wx = x - xf, wy = y - yf;
            const float tw[4] = {(1 - wx) * (1 - wy), wx * (1 - wy),
                                 (1 - wx) * wy,       wx * wy};
            const int xs[4] = {x0, x0 + 1, x0, x0 + 1};
            const int ys[4] = {y0, y0, y0 + 1, y0 + 1};
            float sv0 = 0.f, sv1 = 0.f, sv2 = 0.f, sv3 = 0.f;
#pragma unroll
            for (int tp = 0; tp < 4; ++tp) {
                const int xi = xs[tp], yi = ys[tp];
                if (xi >= 0 && xi < Wd && yi >= 0 && yi < Hd) {
                    const int idx = st + yi * Wd + xi;
                    const uint2 u = *(const uint2*)&val[((size_t)b * LVTOT + idx) * DM + h * HDIM + d4];
                    sv0 = fmaf(tw[tp], b2f((ushort)u.x), sv0);
                    sv1 = fmaf(tw[tp], b2f((ushort)(u.x >> 16)), sv1);
                    sv2 = fmaf(tw[tp], b2f((ushort)u.y), sv2);
                    sv3 = fmaf(tw[tp], b2f((ushort)(u.y >> 16)), sv3);
                }
            }
            acc0 = fmaf(w12, sv0, acc0);
            acc1 = fmaf(w12, sv1, acc1);
            acc2 = fmaf(w12, sv2, acc2);
            acc3 = fmaf(w12, sv3, acc3);
        }
    }
    ushort4 oh, ol;
    split2(acc0, oh.x, ol.x);
    split2(acc1, oh.y, ol.y);
    split2(acc2, oh.z, ol.z);
    split2(acc3, oh.w, ol.w);
    const size_t o = (size_t)row * DM + h * HDIM + d4;
    *(ushort4*)&samph[o] = oh;
    *(ushort4*)&sampl[o] = ol;
}

// ---------------------------------------------------------------------------
// Fused residual add + LayerNorm (fp32). One wave per row.
// ---------------------------------------------------------------------------
__global__ __launch_bounds__(256) void addln_kernel(
    const float* x, const float* __restrict__ dl,
    const float* __restrict__ g, const float* __restrict__ bb,
    float* outf, ushort* __restrict__ outh, ushort* __restrict__ outl,
    const float* __restrict__ qpos, ushort* __restrict__ q2h, ushort* __restrict__ q2l)
{
    const int wv = threadIdx.x >> 6, lane = threadIdx.x & 63;
    const int row = blockIdx.x * 4 + wv;
    const size_t base = (size_t)row * DM + lane * 4;
    const float4 xv = *(const float4*)(x + base);
    const float4 dv = *(const float4*)(dl + base);
    float v[4] = {xv.x + dv.x, xv.y + dv.y, xv.z + dv.z, xv.w + dv.w};

    float s = v[0] + v[1] + v[2] + v[3];
#pragma unroll
    for (int m = 32; m; m >>= 1) s += __shfl_xor(s, m, 64);
    const float mean = s * (1.f / 256.f);
    float sq = 0.f;
#pragma unroll
    for (int j = 0; j < 4; ++j) { float dd = v[j] - mean; sq += dd * dd; }
#pragma unroll
    for (int m = 32; m; m >>= 1) sq += __shfl_xor(sq, m, 64);
    const float rstd = rsqrtf(sq * (1.f / 256.f) + 1e-5f);

    float y[4];
    ushort4 yh, yl;
#pragma unroll
    for (int j = 0; j < 4; ++j) {
        const int col = lane * 4 + j;
        y[j] = (v[j] - mean) * rstd * g[col] + bb[col];
    }
    *(float4*)(outf + base) = make_float4(y[0], y[1], y[2], y[3]);
    split2(y[0], yh.x, yl.x);
    split2(y[1], yh.y, yl.y);
    split2(y[2], yh.z, yl.z);
    split2(y[3], yh.w, yl.w);
    *(ushort4*)(outh + base) = yh;
    *(ushort4*)(outl + base) = yl;
    if (q2h) {
        const float4 qp = *(const float4*)(qpos + base);
        float q2v[4] = {y[0] + qp.x, y[1] + qp.y, y[2] + qp.z, y[3] + qp.w};
        ushort4 qh_, ql_;
        split2(q2v[0], qh_.x, ql_.x);
        split2(q2v[1], qh_.y, ql_.y);
        split2(q2v[2], qh_.z, ql_.z);
        split2(q2v[3], qh_.w, ql_.w);
        *(ushort4*)(q2h + base) = qh_;
        *(ushort4*)(q2l + base) = ql_;
    }
}

// ---------------------------------------------------------------------------
// Fused bbox-head tail + next-layer qpos stage-1. 32 rows/block (grid 150).
// ---------------------------------------------------------------------------
__global__ __launch_bounds__(256) void bbox_fused(
    const ushort* __restrict__ h2h, const ushort* __restrict__ h2l,
    const float* __restrict__ Wb3, const float* __restrict__ bb3,
    const float* __restrict__ rpu, float* __restrict__ refd,
    float* __restrict__ dout, int mode, int writeout,
    const float* __restrict__ Wp1, const float* __restrict__ bp1,
    ushort* __restrict__ t1h, ushort* __restrict__ t1l, int computeT1)
{
    __shared__ float hls[32 * 258];
    __shared__ float wb3s[1024];
    __shared__ float wp1s[4 * 512];
    __shared__ float bp1s[512];
    __shared__ float ref4[32 * 4];

    const int tid = threadIdx.x;
    const int r0 = blockIdx.x * 32;

    if (computeT1) {
        for (int i = tid; i < 2048; i += 256) wp1s[i] = Wp1[i];
        if (tid < 256) { bp1s[tid] = bp1[tid]; bp1s[tid + 256] = bp1[tid + 256]; }
    }
    if (mode == 1) {
        for (int i = tid; i < 1024; i += 256) wb3s[i] = Wb3[i];
        for (int j = tid; j < 1024; j += 256) {
            const int row = j >> 5, seg = (j & 31) * 8;
            const size_t g = (size_t)(r0 + row) * 256 + seg;
            us8 hv = *(const us8*)&h2h[g];
            us8 lv = *(const us8*)&h2l[g];
            float* o = &hls[row * 258 + seg];
#pragma unroll
            for (int x = 0; x < 8; ++x) o[x] = b2f(hv[x]) + b2f(lv[x]);
        }
    }
    __syncthreads();

    if (tid < 128) {
        const int r = tid >> 2, c = tid & 3;
        float v;
        if (mode == 1) {
            float a0 = 0.f, a1 = 0.f, a2 = 0.f, a3 = 0.f;
            const float* hrow = &hls[r * 258];
#pragma unroll 8
            for (int k = 0; k < 256; k += 4) {
                a0 = fmaf(hrow[k + 0], wb3s[(k + 0) * 4 + c], a0);
                a1 = fmaf(hrow[k + 1], wb3s[(k + 1) * 4 + c], a1);
                a2 = fmaf(hrow[k + 2], wb3s[(k + 2) * 4 + c], a2);
                a3 = fmaf(hrow[k + 3], wb3s[(k + 3) * 4 + c], a3);
            }
            const float b3v = (a0 + a1) + (a2 + a3) + bb3[c];
            const float old = refd[(size_t)(r0 + r) * 4 + c];
            const float rc = fminf(fmaxf(old, 0.f), 1.f);
            const float invs = logf(fmaxf(rc, 1e-5f)) - logf(fmaxf(1.f - rc, 1e-5f));
            v = 1.f / (1.f + __expf(-(b3v + invs)));
        } else {
            v = 1.f / (1.f + __expf(-rpu[(size_t)(r0 + r) * 4 + c]));
        }
        refd[(size_t)(r0 + r) * 4 + c] = v;
        if (writeout) dout[(size_t)(r0 + r) * 4 + c] = v;
        ref4[r * 4 + c] = v;
    }
    __syncthreads();

    if (!computeT1) return;
#pragma unroll
    for (int jj = 0; jj < 8; ++jj) {
        const int idx = jj * 2048 + tid * 8;     // 32 rows x 512 cols
        const int row = idx >> 9, nb = idx & 511;
        const float a0 = ref4[row * 4 + 0], a1 = ref4[row * 4 + 1];
        const float a2 = ref4[row * 4 + 2], a3 = ref4[row * 4 + 3];
        us8 hv, lv;
#pragma unroll
        for (int x = 0; x < 8; ++x) {
            const int n = nb + x;
            float t = bp1s[n];
            t = fmaf(a0, wp1s[n], t);
            t = fmaf(a1, wp1s[512 + n], t);
            t = fmaf(a2, wp1s[1024 + n], t);
            t = fmaf(a3, wp1s[1536 + n], t);
            t = fmaxf(t, 0.f);
            ushort hh, ll;
            split2(t, hh, ll);
            hv[x] = hh; lv[x] = ll;
        }
        const size_t gg = (size_t)(r0 + row) * 512 + nb;
        *(us8*)&t1h[gg] = hv;
        *(us8*)&t1l[gg] = lv;
    }
}

// ---------------------------------------------------------------------------
// Host launch
// ---------------------------------------------------------------------------
extern "C" void kernel_launch(void* const* d_in, const int* in_sizes, int n_in,
                              void* d_out, int out_size, void* d_ws, size_t ws_size,
                              hipStream_t stream)
{
    const float* tgt    = (const float*)d_in[0];
    const float* rpu    = (const float*)d_in[1];
    const float* memory = (const float*)d_in[2];
    const float* Wq  = (const float*)d_in[5];  const float* bq  = (const float*)d_in[6];
    const float* Wk  = (const float*)d_in[7];  const float* bk  = (const float*)d_in[8];
    const float* Wv  = (const float*)d_in[9];  const float* bv  = (const float*)d_in[10];
    const float* Wo  = (const float*)d_in[11]; const float* bo  = (const float*)d_in[12];
    const float* ln1g = (const float*)d_in[13]; const float* ln1b = (const float*)d_in[14];
    const float* ln2g = (const float*)d_in[15]; const float* ln2b = (const float*)d_in[16];
    const float* ln3g = (const float*)d_in[17]; const float* ln3b = (const float*)d_in[18];
    const float* Wvp = (const float*)d_in[19]; const float* bvp = (const float*)d_in[20];
    const float* Woff = (const float*)d_in[21]; const float* boff = (const float*)d_in[22];
    const float* Waw = (const float*)d_in[23]; const float* baw = (const float*)d_in[24];
    const float* Wop = (const float*)d_in[25]; const float* bop = (const float*)d_in[26];
    const float* Wff1 = (const float*)d_in[27]; const float* bff1 = (const float*)d_in[28];
    const float* Wff2 = (const float*)d_in[29]; const float* bff2 = (const float*)d_in[30];
    const float* Wb1 = (const float*)d_in[31]; const float* bb1 = (const float*)d_in[32];
    const float* Wb2 = (const float*)d_in[33]; const float* bb2 = (const float*)d_in[34];
    const float* Wb3 = (const float*)d_in[35]; const float* bb3 = (const float*)d_in[36];
    const float* Ws  = (const float*)d_in[37]; const float* bs_ = (const float*)d_in[38];
    const float* Wp1 = (const float*)d_in[39]; const float* bp1 = (const float*)d_in[40];
    const float* Wp2 = (const float*)d_in[41]; const float* bp2 = (const float*)d_in[42];

    size_t off = 0;
    auto alloc = [&](size_t elems, size_t elsz) -> void* {
        void* r = (char*)d_ws + off;
        off += elems * elsz;
        off = (off + 255) & ~(size_t)255;
        return r;
    };
    ushort *wqkh = (ushort*)alloc(6 * 131072, 2);
    ushort *wvh  = (ushort*)alloc(6 * 65536, 2);
    ushort *woh  = (ushort*)alloc(6 * 65536, 2);
    ushort *wvph = (ushort*)alloc(6 * 65536, 2);
    ushort *wfah = (ushort*)alloc(6 * 81920, 2);
    ushort *woph = (ushort*)alloc(6 * 65536, 2);
    ushort *wf1h = (ushort*)alloc(6 * 262144, 2);
    ushort *wf2h = (ushort*)alloc(6 * 262144, 2);
    ushort *wb1h = (ushort*)alloc(6 * 65536, 2);
    ushort *wb2h = (ushort*)alloc(6 * 65536, 2);
    ushort *wsh  = (ushort*)alloc(6 * 20480, 2);
    ushort *wp2h = (ushort*)alloc(131072, 2);
    float  *bqk  = (float*)alloc(6 * 512, 4);
    float  *bfa  = (float*)alloc(6 * 288, 4);

    ushort* mem_bf = (ushort*)alloc((size_t)MEMN * DM, 2);   // 68.8 MB
    ushort* val_bf = (ushort*)alloc((size_t)MEMN * DM, 2);   // 68.8 MB
    float*  out_f  = (float*)alloc(NROW * DM, 4);
    float*  qpos_f = (float*)alloc(NROW * DM, 4);
    float*  tmp_f  = (float*)alloc(NROW * DM, 4);
    float*  refd_f = (float*)alloc(NROW * 4, 4);
    float*  offaw_f = (float*)alloc(NROW * 288, 4);

    ushort* out_h = (ushort*)alloc(NROW * DM, 2);
    ushort* out_l = (ushort*)alloc(NROW * DM, 2);

    // Lifetime-aliased bf16 scratch arena (units of NROW ushorts) — see R3/R4.
    const size_t NN = NROW;
    ushort* scratch = (ushort*)alloc(NN * 2056, 2);
    ushort* q_h  = scratch;
    ushort* q_l  = scratch + NN * 256;
    ushort* vh_h = scratch + NN * 512;
    ushort* att_h = scratch;
    ushort* att_l = scratch + NN * 256;
    ushort* q2_h = scratch + NN * 512;
    ushort* q2_l = scratch + NN * 768;
    ushort* samp_h = scratch;
    ushort* samp_l = scratch + NN * 256;
    ushort* ff_h = scratch;
    ushort* ff_l = scratch + NN * 1024;
    ushort* h1_h = scratch;
    ushort* h1_l = scratch + NN * 256;
    ushort* h2_h = scratch + NN * 512;
    ushort* h2_l = scratch + NN * 768;
    ushort* t1_h = scratch + NN * 1024;
    ushort* t1_l = scratch + NN * 1536;
    ushort* qk_h = scratch + NN * 1024;   // 514*NN needed; t1 dead when written

    if (off > ws_size) return;

    // ---- batched weight transpose (1 dispatch) ----
    {
        TTab tab;
        const float* ss[NTE] = {Wq, Wk, Wv, Wo, Wvp, Woff, Waw, Wop,
                                Wff1, Wff2, Wb1, Wb2, Ws, Wp2};
        ushort* dd[NTE] = {wqkh, wqkh, wvh, woh, wvph, wfah, wfah, woph,
                           wf1h, wf2h, wb1h, wb2h, wsh, wp2h};
        const int KK[NTE]  = {256, 256, 256, 256, 256, 256, 256, 256,
                              256, 1024, 256, 256, 256, 512};
        const int NNe[NTE] = {256, 256, 256, 256, 256, 192, 96, 256,
                              1024, 256, 256, 256, 80, 256};
        const int BB[NTE]  = {6, 6, 6, 6, 6, 6, 6, 6, 6, 6, 6, 6, 6, 1};
        const int DL[NTE]  = {131072, 131072, 65536, 65536, 65536, 81920, 81920,
                              65536, 262144, 262144, 65536, 65536, 20480, 131072};
        const int DR[NTE]  = {0, 256, 0, 0, 0, 0, 192, 0, 0, 0, 0, 0, 0, 0};
        int total = 0;
        for (int e = 0; e < NTE; ++e) {
            tab.s[e] = ss[e]; tab.d[e] = dd[e];
            tab.K[e] = KK[e]; tab.N[e] = NNe[e];
            tab.dls[e] = DL[e]; tab.dr0[e] = DR[e];
            tab.tstart[e] = total;
            total += ((NNe[e] + 31) / 32) * ((KK[e] + 31) / 32) * BB[e];
        }
        tab.tstart[NTE] = total;
        transpose_batch_kernel<<<total, dim3(32, 8), 0, stream>>>(tab);
    }
    concat_both_kernel<<<19, 256, 0, stream>>>(bq, bk, bqk, boff, baw, bfa);
    f2b_kernel<<<(MEMN * DM) / 1024, 256, 0, stream>>>(memory, mem_bf, MEMN * DM);

    hipMemcpyAsync(out_f, tgt, (size_t)NROW * DM * 4, hipMemcpyDeviceToDevice, stream);
    split_kernel<<<(NROW * DM) / 1024, 256, 0, stream>>>(tgt, out_h, out_l, NROW * DM);
    bbox_fused<<<150, 256, 0, stream>>>(nullptr, nullptr, Wb3, bb3, rpu, refd_f,
                                        nullptr, 0, 0, Wp1, bp1, t1_h, t1_l, 1);

    auto GP = [&](const ushort* Ahp, const ushort* Alp, const ushort* BTh,
                  const float* bias, int N, int K, bool relu,
                  float* Cf, ushort* Ch = nullptr, ushort* Cl = nullptr,
                  const float* addsrc = nullptr) {
        dim3 g(NROW / 64, (N + 63) / 64);
        if (relu) gemm_ps<1><<<g, 256, 0, stream>>>(Ahp, Alp, BTh, bias, NROW, N, K,
                                                    Cf, addsrc, Ch, Cl);
        else      gemm_ps<0><<<g, 256, 0, stream>>>(Ahp, Alp, BTh, bias, NROW, N, K,
                                                    Cf, addsrc, Ch, Cl);
    };
    // tiny-tile variant for the low-occupancy call sites (1200 blocks)
    auto GP16 = [&](const ushort* Ahp, const ushort* Alp, const ushort* BTh,
                    const float* bias, int N, int K, bool relu,
                    float* Cf, ushort* Ch = nullptr, ushort* Cl = nullptr,
                    const float* addsrc = nullptr) {
        dim3 g(NROW / 16, (N + 63) / 64);
        if (relu) gemm_ps16<1><<<g, 256, 0, stream>>>(Ahp, Alp, BTh, bias, NROW, N, K,
                                                      Cf, addsrc, Ch, Cl);
        else      gemm_ps16<0><<<g, 256, 0, stream>>>(Ahp, Alp, BTh, bias, NROW, N, K,
                                                      Cf, addsrc, Ch, Cl);
    };

    for (int i = 0; i < NLAYERS; ++i) {
        const ushort* wvp_i = wvph + i * 65536;
        const float*  bvp_i = bvp + i * 256;
        // Wp2 GEMM + val-proj chunk 0 (700 blocks)
        gemm_mix<<<300 + 700, 256, 0, stream>>>(
            t1_h, t1_l, wp2h, bp2, 256, 512, qpos_f, out_f, q_h, q_l,
            300, mem_bf, wvp_i, bvp_i, val_bf, 0);
        // MHA projections: QK (N=512) + V (N=256) in one dispatch
        gemm_qkv<<<dim3(NROW / 64, 12), 256, 0, stream>>>(
            q_h, q_l, out_h, out_l, wqkh + i * 131072, wvh + i * 65536,
            bqk + i * 512, bv + i * 256, qk_h, vh_h);
        mha_mfma_kernel<<<512, 256, 0, stream>>>(qk_h, 512, qk_h + 256, 512,
                                                 vh_h, 256, att_h, att_l);
        // Wo GEMM + val-proj chunk 1
        gemm_mix<<<300 + 700, 256, 0, stream>>>(
            att_h, att_l, woh + i * 65536, bo + i * 256, 256, 256, tmp_f,
            nullptr, nullptr, nullptr,
            300, mem_bf, wvp_i, bvp_i, val_bf, 700);
        addln_kernel<<<1200, 256, 0, stream>>>(out_f, tmp_f, ln1g + i * 256, ln1b + i * 256,
                                               out_f, out_h, out_l, qpos_f, q2_h, q2_l);
        // offaw GEMM + val-proj chunk 2 (completes val_bf before deform)
        gemm_mix<<<375 + 700, 256, 0, stream>>>(
            q2_h, q2_l, wfah + i * 81920, bfa + i * 288, 288, 256, offaw_f,
            nullptr, nullptr, nullptr,
            375, mem_bf, wvp_i, bvp_i, val_bf, 1400);
        deform_kernel<<<1200, 256, 0, stream>>>(val_bf, offaw_f, refd_f, samp_h, samp_l);
        GP16(samp_h, samp_l, woph + i * 65536, bop + i * 256, 256, 256, false, tmp_f);
        addln_kernel<<<1200, 256, 0, stream>>>(out_f, tmp_f, ln2g + i * 256, ln2b + i * 256,
                                               out_f, out_h, out_l, nullptr, nullptr, nullptr);
        // FFN
        GP(out_h, out_l, wf1h + i * 262144, bff1 + i * 1024, 1024, 256, true,
           nullptr, ff_h, ff_l);
        GP16(ff_h, ff_l, wf2h + i * 262144, bff2 + i * 256, 256, 1024, false, tmp_f);
        addln_kernel<<<1200, 256, 0, stream>>>(out_f, tmp_f, ln3g + i * 256, ln3b + i * 256,
                                               out_f, out_h, out_l, nullptr, nullptr, nullptr);
        // bbox head
        GP16(out_h, out_l, wb1h + i * 65536, bb1 + i * 256, 256, 256, true,
             nullptr, h1_h, h1_l);
        GP16(h1_h, h1_l, wb2h + i * 65536, bb2 + i * 256, 256, 256, true,
             nullptr, h2_h, h2_l);
        const int last = (i == NLAYERS - 1);
        bbox_fused<<<150, 256, 0, stream>>>(h2_h, h2_l, Wb3 + i * 1024, bb3 + i * 4,
                                            nullptr, refd_f, (float*)d_out, 1,
                                            last ? 1 : 0, Wp1, bp1, t1_h, t1_l,
                                            last ? 0 : 1);
        if (last) {
            GP16(out_h, out_l, wsh + i * 20480, bs_ + i * 80, 80, 256, false,
                 (float*)d_out + NROW * 4);
        }
    }
}

// Round 12
// 1712.418 us; speedup vs baseline: 1.0176x; 1.0176x over previous
//
#include <hip/hip_runtime.h>

#define NLAYERS 6
#define BSZ 16
#define NQL 300
#define DM 256
#define NHEAD 8
#define HDIM 32
#define NLVL 3
#define NPT 4
#define DFFN 1024
#define NCLS 80
#define LVTOT 8400
#define NROW (BSZ * NQL)   // 4800
#define MEMN (BSZ * LVTOT) // 134400

typedef __attribute__((ext_vector_type(8))) short bf16x8;
typedef __attribute__((ext_vector_type(8))) ushort us8;
typedef __attribute__((ext_vector_type(4))) float f32x4;

__device__ __forceinline__ float b2f(ushort u) {
    return __uint_as_float(((uint)u) << 16);
}
__device__ __forceinline__ ushort f2b(float f) {
    uint i = __float_as_uint(f);
    uint r = i + 0x7fffu + ((i >> 16) & 1u);   // RNE
    return (ushort)(r >> 16);
}
__device__ __forceinline__ void split2(float v, ushort& h, ushort& l) {
    ushort hh = f2b(v);
    h = hh;
    l = f2b(v - b2f(hh));
}
// async global -> LDS, 16 bytes per lane (LDS dest = wave base + lane*16)
__device__ __forceinline__ void gl_lds16(const void* g, void* l) {
    __builtin_amdgcn_global_load_lds(
        (const __attribute__((address_space(1))) unsigned int*)g,
        (__attribute__((address_space(3))) unsigned int*)l, 16, 0, 0);
}

// ---------------------------------------------------------------------------
// fp32 -> bf16 plane (4 elems/thread)
// ---------------------------------------------------------------------------
__global__ __launch_bounds__(256) void f2b_kernel(
    const float* __restrict__ src, ushort* __restrict__ dst, int n)
{
    int i = (blockIdx.x * 256 + threadIdx.x) * 4;
    if (i < n) {
        float4 v = *(const float4*)&src[i];
        ushort4 o = {f2b(v.x), f2b(v.y), f2b(v.z), f2b(v.w)};
        *(ushort4*)&dst[i] = o;
    }
}

// fp32 -> bf16 hi + lo planes (4 elems/thread)
__global__ __launch_bounds__(256) void split_kernel(
    const float* __restrict__ src, ushort* __restrict__ dh,
    ushort* __restrict__ dl, int n)
{
    int i = (blockIdx.x * 256 + threadIdx.x) * 4;
    if (i < n) {
        float4 v = *(const float4*)&src[i];
        ushort4 h, l;
        split2(v.x, h.x, l.x);
        split2(v.y, h.y, l.y);
        split2(v.z, h.z, l.z);
        split2(v.w, h.w, l.w);
        *(ushort4*)&dh[i] = h;
        *(ushort4*)&dl[i] = l;
    }
}

// ---------------------------------------------------------------------------
// Batched transpose + bf16-hi: one dispatch for all weight preprocessing.
// ---------------------------------------------------------------------------
#define NTE 14
struct TTab {
    const float* s[NTE];
    ushort* d[NTE];
    int K[NTE], N[NTE], dls[NTE], dr0[NTE];
    int tstart[NTE + 1];
};

__global__ __launch_bounds__(256) void transpose_batch_kernel(TTab tab)
{
    __shared__ float tile[32][33];
    const int bx = blockIdx.x;
    int e = 0;
    while (e < NTE - 1 && bx >= tab.tstart[e + 1]) ++e;
    const int local = bx - tab.tstart[e];
    const int K = tab.K[e], N = tab.N[e];
    const int tx_n = (N + 31) >> 5, ty_n = (K + 31) >> 5;
    const int perB = tx_n * ty_n;
    const int z = local / perB;
    const int rem = local - z * perB;
    const int tyi = rem / tx_n, txi = rem - tyi * tx_n;
    const float* src = tab.s[e] + (size_t)z * K * N;
    ushort* dh = tab.d[e] + (size_t)z * tab.dls[e] + (size_t)tab.dr0[e] * K;
    const int n0 = txi * 32, k0 = tyi * 32;
    const int tx = threadIdx.x, ty = threadIdx.y;   // 32 x 8
    for (int r = 0; r < 32; r += 8) {
        int k = k0 + ty + r, n = n0 + tx;
        if (k < K && n < N) tile[ty + r][tx] = src[(size_t)k * N + n];
    }
    __syncthreads();
    for (int r = 0; r < 32; r += 8) {
        int n = n0 + ty + r, k = k0 + tx;
        if (n < N && k < K) dh[(size_t)n * K + k] = f2b(tile[tx][ty + r]);
    }
}

// ---------------------------------------------------------------------------
// Both bias concats in one dispatch (12 + 7 blocks)
// ---------------------------------------------------------------------------
__global__ __launch_bounds__(256) void concat_both_kernel(
    const float* __restrict__ bq, const float* __restrict__ bk, float* __restrict__ bqk,
    const float* __restrict__ boff, const float* __restrict__ baw, float* __restrict__ bfa)
{
    const int bx = blockIdx.x;
    if (bx < 12) {
        int i = bx * 256 + threadIdx.x;
        if (i < 6 * 512) {
            int l = i / 512, j = i - l * 512;
            bqk[i] = (j < 256) ? bq[l * 256 + j] : bk[l * 256 + j - 256];
        }
    } else {
        int i = (bx - 12) * 256 + threadIdx.x;
        if (i < 6 * 288) {
            int l = i / 288, j = i - l * 288;
            bfa[i] = (j < 192) ? boff[l * 192 + j] : baw[l * 96 + j - 192];
        }
    }
}

// ---------------------------------------------------------------------------
// Pre-split-A MFMA GEMM (64x64 tile, double-buffered, fully async staging).
// ---------------------------------------------------------------------------
template <int ACT>
__global__ __launch_bounds__(256) void gemm_ps(
    const ushort* __restrict__ Ahp, const ushort* __restrict__ Alp,
    const ushort* __restrict__ BTh, const float* __restrict__ bias,
    int M, int N, int K,
    float* __restrict__ Cf, const float* __restrict__ addsrc,
    ushort* __restrict__ Ch, ushort* __restrict__ Cl)
{
    __shared__ __align__(16) ushort Ahs[2][64 * 32];
    __shared__ __align__(16) ushort Als[2][64 * 32];
    __shared__ __align__(16) ushort Bhs[2][64 * 32];

    const int tid  = threadIdx.x;
    const int m0   = blockIdx.x * 64;
    const int n0   = blockIdx.y * 64;
    const int wv   = tid >> 6;
    const int lane = tid & 63;
    const int lm   = lane & 15;
    const int lq   = lane >> 4;
    const int r    = tid >> 2;
    const int c8   = (tid & 3) * 8;

    gl_lds16(&Ahp[(size_t)(m0 + r) * K + c8], &Ahs[0][r * 32 + c8]);
    gl_lds16(&Alp[(size_t)(m0 + r) * K + c8], &Als[0][r * 32 + c8]);
    gl_lds16(&BTh[(size_t)(n0 + r) * K + c8], &Bhs[0][r * 32 + c8]);
    __syncthreads();

    f32x4 acc[4] = {};
    int buf = 0;
    for (int k0 = 32; k0 < K + 32; k0 += 32) {
        const int nxt = buf ^ 1;
        if (k0 < K) {
            gl_lds16(&Ahp[(size_t)(m0 + r) * K + k0 + c8], &Ahs[nxt][r * 32 + c8]);
            gl_lds16(&Alp[(size_t)(m0 + r) * K + k0 + c8], &Als[nxt][r * 32 + c8]);
            gl_lds16(&BTh[(size_t)(n0 + r) * K + k0 + c8], &Bhs[nxt][r * 32 + c8]);
        }
        bf16x8 afh = *(const bf16x8*)&Ahs[buf][(wv * 16 + lm) * 32 + lq * 8];
        bf16x8 afl = *(const bf16x8*)&Als[buf][(wv * 16 + lm) * 32 + lq * 8];
#pragma unroll
        for (int nb = 0; nb < 4; ++nb) {
            bf16x8 bfh = *(const bf16x8*)&Bhs[buf][(nb * 16 + lm) * 32 + lq * 8];
            acc[nb] = __builtin_amdgcn_mfma_f32_16x16x32_bf16(afh, bfh, acc[nb], 0, 0, 0);
            acc[nb] = __builtin_amdgcn_mfma_f32_16x16x32_bf16(afl, bfh, acc[nb], 0, 0, 0);
        }
        __syncthreads();
        buf = nxt;
    }

    const int row = m0 + wv * 16 + lq * 4;
#pragma unroll
    for (int nb = 0; nb < 4; ++nb) {
        int col = n0 + nb * 16 + lm;
        if (col < N) {
            float bv = bias ? bias[col] : 0.f;
#pragma unroll
            for (int rr = 0; rr < 4; ++rr) {
                float v = acc[nb][rr] + bv;
                if (ACT) v = fmaxf(v, 0.f);
                const size_t idx = (size_t)(row + rr) * N + col;
                if (Cf) Cf[idx] = v;
                if (Ch) {
                    float w = addsrc ? (v + addsrc[idx]) : v;
                    ushort h, l;
                    split2(w, h, l);
                    Ch[idx] = h;
                    if (Cl) Cl[idx] = l;
                }
            }
        }
    }
}

// ---------------------------------------------------------------------------
// Tiny-tile pre-split GEMM (16x64, double-buffered). Grid (M/16, N/64) ->
// ~4.7 waves/SIMD at the low-occupancy call sites.
// ---------------------------------------------------------------------------
template <int ACT>
__global__ __launch_bounds__(256) void gemm_ps16(
    const ushort* __restrict__ Ahp, const ushort* __restrict__ Alp,
    const ushort* __restrict__ BTh, const float* __restrict__ bias,
    int M, int N, int K,
    float* __restrict__ Cf, const float* __restrict__ addsrc,
    ushort* __restrict__ Ch, ushort* __restrict__ Cl)
{
    __shared__ __align__(16) ushort Ahs[2][16 * 32];
    __shared__ __align__(16) ushort Als[2][16 * 32];
    __shared__ __align__(16) ushort Bhs[2][64 * 32];

    const int tid  = threadIdx.x;
    const int m0   = blockIdx.x * 16;
    const int n0   = blockIdx.y * 64;
    const int wv   = tid >> 6;
    const int lane = tid & 63;
    const int lm   = lane & 15;
    const int lq   = lane >> 4;
    const int ra   = (tid & 63) >> 2;    // 0..15 (A rows; tid<64 -> Ah, tid<128 -> Al)
    const int rb   = tid >> 2;           // 0..63 (B rows)
    const int c8   = (tid & 3) * 8;

    if (tid < 64)        gl_lds16(&Ahp[(size_t)(m0 + ra) * K + c8], &Ahs[0][ra * 32 + c8]);
    else if (tid < 128)  gl_lds16(&Alp[(size_t)(m0 + ra) * K + c8], &Als[0][ra * 32 + c8]);
    gl_lds16(&BTh[(size_t)(n0 + rb) * K + c8], &Bhs[0][rb * 32 + c8]);
    __syncthreads();

    f32x4 acc = {};
    int buf = 0;
    for (int k0 = 32; k0 < K + 32; k0 += 32) {
        const int nxt = buf ^ 1;
        if (k0 < K) {
            if (tid < 64)       gl_lds16(&Ahp[(size_t)(m0 + ra) * K + k0 + c8], &Ahs[nxt][ra * 32 + c8]);
            else if (tid < 128) gl_lds16(&Alp[(size_t)(m0 + ra) * K + k0 + c8], &Als[nxt][ra * 32 + c8]);
            gl_lds16(&BTh[(size_t)(n0 + rb) * K + k0 + c8], &Bhs[nxt][rb * 32 + c8]);
        }
        bf16x8 bfh = *(const bf16x8*)&Bhs[buf][(wv * 16 + lm) * 32 + lq * 8];
        bf16x8 afh = *(const bf16x8*)&Ahs[buf][lm * 32 + lq * 8];
        bf16x8 afl = *(const bf16x8*)&Als[buf][lm * 32 + lq * 8];
        acc = __builtin_amdgcn_mfma_f32_16x16x32_bf16(afh, bfh, acc, 0, 0, 0);
        acc = __builtin_amdgcn_mfma_f32_16x16x32_bf16(afl, bfh, acc, 0, 0, 0);
        __syncthreads();
        buf = nxt;
    }

    const int col = n0 + wv * 16 + lm;
    if (col < N) {
        const float bv = bias ? bias[col] : 0.f;
        const int row = m0 + lq * 4;
#pragma unroll
        for (int rr = 0; rr < 4; ++rr) {
            float v = acc[rr] + bv;
            if (ACT) v = fmaxf(v, 0.f);
            const size_t idx = (size_t)(row + rr) * N + col;
            if (Cf) Cf[idx] = v;
            if (Ch) {
                float w = addsrc ? (v + addsrc[idx]) : v;
                ushort h, l;
                split2(w, h, l);
                Ch[idx] = h;
                if (Cl) Cl[idx] = l;
            }
        }
    }
}

// ---------------------------------------------------------------------------
// Mixed dispatch: small 64x64 GEMM (no act) + chunk of the 128x128 val-proj
// GEMM (M=MEMN, N=256, K=256). Single-buffered big path (24 KB union):
// val-proj is HBM-bound, dbuf only costs occupancy (R11 lesson).
// ---------------------------------------------------------------------------
__global__ __launch_bounds__(256) void gemm_mix(
    const ushort* __restrict__ Ahp, const ushort* __restrict__ Alp,
    const ushort* __restrict__ BTh, const float* __restrict__ bias,
    int N, int K,
    float* __restrict__ Cf, const float* __restrict__ addsrc,
    ushort* __restrict__ Ch, ushort* __restrict__ Cl,
    int nSmall,
    const ushort* __restrict__ gA, const ushort* __restrict__ gB,
    const float* __restrict__ gbias, ushort* __restrict__ gC,
    int chunkOff)
{
    __shared__ __align__(16) ushort lds[12288];   // 24 KB

    const int tid  = threadIdx.x;
    const int wv   = tid >> 6;
    const int lane = tid & 63;
    const int lm   = lane & 15;
    const int lq   = lane >> 4;

    if ((int)blockIdx.x < nSmall) {
        typedef ushort (*lds2)[64 * 32];
        lds2 Ahs = (lds2)lds;
        lds2 Als = (lds2)(lds + 4096);
        lds2 Bhs = (lds2)(lds + 8192);
        const int m0 = (blockIdx.x % 75) * 64;
        const int n0 = (blockIdx.x / 75) * 64;
        const int r  = tid >> 2;
        const int c8 = (tid & 3) * 8;

        gl_lds16(&Ahp[(size_t)(m0 + r) * K + c8], &Ahs[0][r * 32 + c8]);
        gl_lds16(&Alp[(size_t)(m0 + r) * K + c8], &Als[0][r * 32 + c8]);
        gl_lds16(&BTh[(size_t)(n0 + r) * K + c8], &Bhs[0][r * 32 + c8]);
        __syncthreads();

        f32x4 acc[4] = {};
        int buf = 0;
        for (int k0 = 32; k0 < K + 32; k0 += 32) {
            const int nxt = buf ^ 1;
            if (k0 < K) {
                gl_lds16(&Ahp[(size_t)(m0 + r) * K + k0 + c8], &Ahs[nxt][r * 32 + c8]);
                gl_lds16(&Alp[(size_t)(m0 + r) * K + k0 + c8], &Als[nxt][r * 32 + c8]);
                gl_lds16(&BTh[(size_t)(n0 + r) * K + k0 + c8], &Bhs[nxt][r * 32 + c8]);
            }
            bf16x8 afh = *(const bf16x8*)&Ahs[buf][(wv * 16 + lm) * 32 + lq * 8];
            bf16x8 afl = *(const bf16x8*)&Als[buf][(wv * 16 + lm) * 32 + lq * 8];
#pragma unroll
            for (int nb = 0; nb < 4; ++nb) {
                bf16x8 bfh = *(const bf16x8*)&Bhs[buf][(nb * 16 + lm) * 32 + lq * 8];
                acc[nb] = __builtin_amdgcn_mfma_f32_16x16x32_bf16(afh, bfh, acc[nb], 0, 0, 0);
                acc[nb] = __builtin_amdgcn_mfma_f32_16x16x32_bf16(afl, bfh, acc[nb], 0, 0, 0);
            }
            __syncthreads();
            buf = nxt;
        }

        const int row = m0 + wv * 16 + lq * 4;
#pragma unroll
        for (int nb = 0; nb < 4; ++nb) {
            int col = n0 + nb * 16 + lm;
            if (col < N) {
                float bv = bias[col];
#pragma unroll
                for (int rr = 0; rr < 4; ++rr) {
                    float v = acc[nb][rr] + bv;
                    const size_t idx = (size_t)(row + rr) * N + col;
                    if (Cf) Cf[idx] = v;
                    if (Ch) {
                        float w = addsrc ? (v + addsrc[idx]) : v;
                        ushort h, l;
                        split2(w, h, l);
                        Ch[idx] = h;
                        if (Cl) Cl[idx] = l;
                    }
                }
            }
        }
    } else {
        ushort* As = lds;
        ushort* Bs = lds + 4096;
        const int bid = (int)blockIdx.x - nSmall + chunkOff;
        const int n0 = (bid & 1) * 128;
        const int m0 = (bid >> 1) * 128;
        const int wr = wv >> 1, wc = wv & 1;
        const int srow = lane >> 2;
        const int scol = (lane & 3) * 8;

        f32x4 acc[4][4] = {};

        for (int k0 = 0; k0 < 256; k0 += 32) {
            __syncthreads();
#pragma unroll
            for (int s2 = 0; s2 < 2; ++s2) {
                const int seg = wv * 2 + s2;
                const int row = seg * 16 + srow;
                gl_lds16(&gA[(size_t)(m0 + row) * 256 + k0 + scol],
                         &As[seg * 512 + lane * 8]);
                gl_lds16(&gB[(size_t)(n0 + row) * 256 + k0 + scol],
                         &Bs[seg * 512 + lane * 8]);
            }
            __syncthreads();

            bf16x8 af[4], bfr[4];
#pragma unroll
            for (int i = 0; i < 4; ++i)
                af[i] = *(const bf16x8*)&As[(wr * 64 + i * 16 + lm) * 32 + lq * 8];
#pragma unroll
            for (int i = 0; i < 4; ++i)
                bfr[i] = *(const bf16x8*)&Bs[(wc * 64 + i * 16 + lm) * 32 + lq * 8];
#pragma unroll
            for (int mi = 0; mi < 4; ++mi)
#pragma unroll
                for (int ni = 0; ni < 4; ++ni)
                    acc[mi][ni] = __builtin_amdgcn_mfma_f32_16x16x32_bf16(
                        af[mi], bfr[ni], acc[mi][ni], 0, 0, 0);
        }

#pragma unroll
        for (int ni = 0; ni < 4; ++ni) {
            const int col = n0 + wc * 64 + ni * 16 + lm;
            const float bv = gbias[col];
#pragma unroll
            for (int mi = 0; mi < 4; ++mi) {
                const int row = m0 + wr * 64 + mi * 16 + lq * 4;
#pragma unroll
                for (int rr = 0; rr < 4; ++rr)
                    gC[(size_t)(row + rr) * 256 + col] = f2b(acc[mi][ni][rr] + bv);
            }
        }
    }
}

// ---------------------------------------------------------------------------
// Merged QK + V projection GEMM: one dispatch, grid (75, 12).
// ---------------------------------------------------------------------------
__global__ __launch_bounds__(256) void gemm_qkv(
    const ushort* __restrict__ qhp, const ushort* __restrict__ qlp,
    const ushort* __restrict__ ohp, const ushort* __restrict__ olp,
    const ushort* __restrict__ Bqk, const ushort* __restrict__ Bv,
    const float* __restrict__ biasqk, const float* __restrict__ biasv,
    ushort* __restrict__ Cqk, ushort* __restrict__ Cv)
{
    constexpr int K = 256;
    __shared__ __align__(16) ushort Ahs[2][64 * 32];
    __shared__ __align__(16) ushort Als[2][64 * 32];
    __shared__ __align__(16) ushort Bhs[2][64 * 32];

    const int by = blockIdx.y;
    const ushort *Ahp, *Alp, *BTh;
    const float* bias;
    ushort* Ch;
    int N, n0;
    if (by < 8) { Ahp = qhp; Alp = qlp; BTh = Bqk; bias = biasqk; Ch = Cqk; N = 512; n0 = by * 64; }
    else        { Ahp = ohp; Alp = olp; BTh = Bv;  bias = biasv;  Ch = Cv;  N = 256; n0 = (by - 8) * 64; }

    const int tid  = threadIdx.x;
    const int m0   = blockIdx.x * 64;
    const int wv   = tid >> 6;
    const int lane = tid & 63;
    const int lm   = lane & 15;
    const int lq   = lane >> 4;
    const int r    = tid >> 2;
    const int c8   = (tid & 3) * 8;

    gl_lds16(&Ahp[(size_t)(m0 + r) * K + c8], &Ahs[0][r * 32 + c8]);
    gl_lds16(&Alp[(size_t)(m0 + r) * K + c8], &Als[0][r * 32 + c8]);
    gl_lds16(&BTh[(size_t)(n0 + r) * K + c8], &Bhs[0][r * 32 + c8]);
    __syncthreads();

    f32x4 acc[4] = {};
    int buf = 0;
    for (int k0 = 32; k0 < K + 32; k0 += 32) {
        const int nxt = buf ^ 1;
        if (k0 < K) {
            gl_lds16(&Ahp[(size_t)(m0 + r) * K + k0 + c8], &Ahs[nxt][r * 32 + c8]);
            gl_lds16(&Alp[(size_t)(m0 + r) * K + k0 + c8], &Als[nxt][r * 32 + c8]);
            gl_lds16(&BTh[(size_t)(n0 + r) * K + k0 + c8], &Bhs[nxt][r * 32 + c8]);
        }
        bf16x8 afh = *(const bf16x8*)&Ahs[buf][(wv * 16 + lm) * 32 + lq * 8];
        bf16x8 afl = *(const bf16x8*)&Als[buf][(wv * 16 + lm) * 32 + lq * 8];
#pragma unroll
        for (int nb = 0; nb < 4; ++nb) {
            bf16x8 bfh = *(const bf16x8*)&Bhs[buf][(nb * 16 + lm) * 32 + lq * 8];
            acc[nb] = __builtin_amdgcn_mfma_f32_16x16x32_bf16(afh, bfh, acc[nb], 0, 0, 0);
            acc[nb] = __builtin_amdgcn_mfma_f32_16x16x32_bf16(afl, bfh, acc[nb], 0, 0, 0);
        }
        __syncthreads();
        buf = nxt;
    }

    const int row = m0 + wv * 16 + lq * 4;
#pragma unroll
    for (int nb = 0; nb < 4; ++nb) {
        const int col = n0 + nb * 16 + lm;
        const float bv = bias[col];
#pragma unroll
        for (int rr = 0; rr < 4; ++rr)
            Ch[(size_t)(row + rr) * N + col] = f2b(acc[nb][rr] + bv);
    }
}

// ---------------------------------------------------------------------------
// MFMA MHA: one block per (b, h, q-QUARTER); grid 512 = 2 blocks/CU.
// ---------------------------------------------------------------------------
__global__ __launch_bounds__(256) void mha_mfma_kernel(
    const ushort* __restrict__ qh, int ldq, const ushort* __restrict__ kh, int ldk,
    const ushort* __restrict__ vh, int ldv,
    ushort* __restrict__ outh, ushort* __restrict__ outl)
{
    __shared__ ushort Kh[304 * 36];
    __shared__ ushort Vth[32 * 328];
    __shared__ ushort Pb[4][16 * 168];

    const int tid = threadIdx.x;
    const int wv = tid >> 6, lane = tid & 63;
    const int bh = blockIdx.x >> 2, quarter = blockIdx.x & 3;
    const int b = bh >> 3, h = bh & 7;
    const size_t qbase = (size_t)b * NQL * ldq + h * HDIM;
    const size_t kbase = (size_t)b * NQL * ldk + h * HDIM;
    const size_t vbase = (size_t)b * NQL * ldv + h * HDIM;
    const size_t obase = (size_t)b * NQL * DM + h * HDIM;

    for (int idx = tid; idx < 304 * 4; idx += 256) {
        const int row = idx >> 2, d0 = (idx & 3) * 8;
        us8 v = {};
        if (row < NQL) v = *(const us8*)&kh[kbase + (size_t)row * ldk + d0];
        ushort* o = &Kh[row * 36 + d0];
#pragma unroll
        for (int x = 0; x < 8; ++x) o[x] = v[x];
    }
    for (int idx = tid; idx < 328 * 4; idx += 256) {
        const int key = idx >> 2, d0 = (idx & 3) * 8;
        us8 v = {};
        if (key < NQL) v = *(const us8*)&vh[vbase + (size_t)key * ldv + d0];
#pragma unroll
        for (int x = 0; x < 8; ++x) Vth[(d0 + x) * 328 + key] = v[x];
    }
    for (int i = lane; i < 16 * 168; i += 64) Pb[wv][i] = 0;
    __syncthreads();

    const int quad = lane >> 4, c = lane & 15;
    const float scale = 0.17677669529663687f;

    const int qt_beg = quarter * 5 + wv;
    const int qt_end = min(quarter * 5 + 5, 19);
    for (int qt = qt_beg; qt < qt_end; qt += 4) {
        const int q = qt * 16 + c;
        bf16x8 qf = *(const bf16x8*)&qh[qbase + (size_t)q * ldq + quad * 8];

        f32x4 sc[19];
#pragma unroll
        for (int kt = 0; kt < 19; ++kt) {
            bf16x8 kf = *(const bf16x8*)&Kh[(kt * 16 + c) * 36 + quad * 8];
            f32x4 a = {};
            a = __builtin_amdgcn_mfma_f32_16x16x32_bf16(qf, kf, a, 0, 0, 0);
            sc[kt] = a;
        }
        float inv4[4];
#pragma unroll
        for (int r = 0; r < 4; ++r) {
            float mx = -1e30f;
#pragma unroll
            for (int kt = 0; kt < 19; ++kt) {
                float s = sc[kt][r] * scale;
                if (kt * 16 + c >= NQL) s = -1e30f;
                sc[kt][r] = s;
                mx = fmaxf(mx, s);
            }
#pragma unroll
            for (int m = 1; m < 16; m <<= 1) mx = fmaxf(mx, __shfl_xor(mx, m, 64));
            float l = 0.f;
#pragma unroll
            for (int kt = 0; kt < 19; ++kt) {
                float p = __expf(sc[kt][r] - mx);
                sc[kt][r] = p;
                l += p;
            }
#pragma unroll
            for (int m = 1; m < 16; m <<= 1) l += __shfl_xor(l, m, 64);
            inv4[r] = 1.f / l;
        }

        f32x4 o0 = {}, o1 = {};
#pragma unroll
        for (int r = 0; r < 4; ++r)
#pragma unroll
            for (int kt = 0; kt < 10; ++kt)
                Pb[wv][(quad * 4 + r) * 168 + kt * 16 + c] = f2b(sc[kt][r] * inv4[r]);
#pragma unroll
        for (int ks = 0; ks < 5; ++ks) {
            bf16x8 pf = *(const bf16x8*)&Pb[wv][c * 168 + ks * 32 + quad * 8];
            bf16x8 v0 = *(const bf16x8*)&Vth[c * 328 + ks * 32 + quad * 8];
            bf16x8 v1 = *(const bf16x8*)&Vth[(16 + c) * 328 + ks * 32 + quad * 8];
            o0 = __builtin_amdgcn_mfma_f32_16x16x32_bf16(pf, v0, o0, 0, 0, 0);
            o1 = __builtin_amdgcn_mfma_f32_16x16x32_bf16(pf, v1, o1, 0, 0, 0);
        }
#pragma unroll
        for (int r = 0; r < 4; ++r) {
#pragma unroll
            for (int kt = 10; kt < 19; ++kt)
                Pb[wv][(quad * 4 + r) * 168 + (kt - 10) * 16 + c] = f2b(sc[kt][r] * inv4[r]);
            Pb[wv][(quad * 4 + r) * 168 + 144 + c] = 0;
        }
#pragma unroll
        for (int ks = 0; ks < 5; ++ks) {
            bf16x8 pf = *(const bf16x8*)&Pb[wv][c * 168 + ks * 32 + quad * 8];
            bf16x8 v0 = *(const bf16x8*)&Vth[c * 328 + 160 + ks * 32 + quad * 8];
            bf16x8 v1 = *(const bf16x8*)&Vth[(16 + c) * 328 + 160 + ks * 32 + quad * 8];
            o0 = __builtin_amdgcn_mfma_f32_16x16x32_bf16(pf, v0, o0, 0, 0, 0);
            o1 = __builtin_amdgcn_mfma_f32_16x16x32_bf16(pf, v1, o1, 0, 0, 0);
        }
#pragma unroll
        for (int r = 0; r < 4; ++r) {
            const int qq = qt * 16 + quad * 4 + r;
            if (qq < NQL) {
                ushort hh, ll;
                split2(o0[r], hh, ll);
                outh[obase + (size_t)qq * DM + c] = hh;
                outl[obase + (size_t)qq * DM + c] = ll;
                split2(o1[r], hh, ll);
                outh[obase + (size_t)qq * DM + 16 + c] = hh;
                outl[obase + (size_t)qq * DM + 16 + c] = ll;
            }
        }
    }
}

// ---------------------------------------------------------------------------
// Deformable sampling — 4 rows/block (grid 1200), 4 adjacent d per thread
// via aligned uint2 loads. Per-element FP order identical.
// ---------------------------------------------------------------------------
__global__ __launch_bounds__(256) void deform_kernel(
    const ushort* __restrict__ val, const float* __restrict__ offaw,
    const float* __restrict__ refd,
    ushort* __restrict__ samph, ushort* __restrict__ sampl)
{
    __shared__ float offs[4][192];
    __shared__ float aws[4][96];
    __shared__ float rr4[4][4];
    const int row0 = blockIdx.x * 4;
    const int t = threadIdx.x;
    for (int i = t; i < 4 * 288; i += 256) {
        const int rh = i / 288, j = i - rh * 288;
        const float v = offaw[(size_t)(row0 + rh) * 288 + j];
        if (j < 192) offs[rh][j] = v;
        else         aws[rh][j - 192] = v;
    }
    if (t < 16) rr4[t >> 2][t & 3] = refd[(size_t)(row0 + (t >> 2)) * 4 + (t & 3)];
    __syncthreads();

    const int sub = t >> 6;              // row within the quad
    const int row = row0 + sub;
    const int b = row / NQL;
    const int t6 = t & 63;
    const int h = t6 >> 3;               // 0..7
    const int d4 = (t6 & 7) * 4;         // 0,4,..,28

    float mx = -1e30f;
#pragma unroll
    for (int j = 0; j < 12; ++j) mx = fmaxf(mx, aws[sub][h * 12 + j]);
    float ev[12]; float se = 0.f;
#pragma unroll
    for (int j = 0; j < 12; ++j) { ev[j] = __expf(aws[sub][h * 12 + j] - mx); se += ev[j]; }
    const float inv = 1.f / se;

    const float r0 = rr4[sub][0], r1 = rr4[sub][1];
    const float r2 = rr4[sub][2], r3 = rr4[sub][3];

    const int HWs[3] = {80, 40, 20};
    const int STs[3] = {0, 6400, 8000};
    float acc0 = 0.f, acc1 = 0.f, acc2 = 0.f, acc3 = 0.f;
#pragma unroll
    for (int l = 0; l < NLVL; ++l) {
        const int Wd = HWs[l], Hd = HWs[l], st = STs[l];
#pragma unroll
        for (int p = 0; p < NPT; ++p) {
            const float w12 = ev[l * 4 + p] * inv;
            const float ox = offs[sub][((h * 3 + l) * 4 + p) * 2 + 0];
            const float oy = offs[sub][((h * 3 + l) * 4 + p) * 2 + 1];
            const float x = (r0 + ox * 0.125f * r2) * Wd - 0.5f;
            const float y = (r1 + oy * 0.125f * r3) * Hd - 0.5f;
            const float xf = floorf(x), yf = floorf(y);
            const int x0 = (int)xf, y0 = (int)yf;
            const float wx = x - xf, wy = y - yf;
            const float tw[4] = {(1 - wx) * (1 - wy), wx * (1 - wy),
                                 (1 - wx) * wy,       wx * wy};
            const int xs[4] = {x0, x0 + 1, x0, x0 + 1};
            const int ys[4] = {y0, y0, y0 + 1, y0 + 1};
            float sv0 = 0.f, sv1 = 0.f, sv2 = 0.f, sv3 = 0.f;
#pragma unroll
            for (int tp = 0; tp < 4; ++tp) {
                const int xi = xs[tp], yi = ys[tp];
                if (xi >= 0 && xi < Wd && yi >= 0 && yi < Hd) {
                    const int idx = st + yi * Wd + xi;
                    const uint2 u = *(const uint2*)&val[((size_t)b * LVTOT + idx) * DM + h * HDIM + d4];
                    sv0 = fmaf(tw[tp], b2f((ushort)u.x), sv0);
                    sv1 = fmaf(tw[tp], b2f((ushort)(u.x >> 16)), sv1);
                    sv2 = fmaf(tw[tp], b2f((ushort)u.y), sv2);
                    sv3 = fmaf(tw[tp], b2f((ushort)(u.y >> 16)), sv3);
                }
            }
            acc0 = fmaf(w12, sv0, acc0);
            acc1 = fmaf(w12, sv1, acc1);
            acc2 = fmaf(w12, sv2, acc2);
            acc3 = fmaf(w12, sv3, acc3);
        }
    }
    ushort4 oh, ol;
    split2(acc0, oh.x, ol.x);
    split2(acc1, oh.y, ol.y);
    split2(acc2, oh.z, ol.z);
    split2(acc3, oh.w, ol.w);
    const size_t o = (size_t)row * DM + h * HDIM + d4;
    *(ushort4*)&samph[o] = oh;
    *(ushort4*)&sampl[o] = ol;
}

// ---------------------------------------------------------------------------
// Fused residual add + LayerNorm (fp32). One wave per row.
// ---------------------------------------------------------------------------
__global__ __launch_bounds__(256) void addln_kernel(
    const float* x, const float* __restrict__ dl,
    const float* __restrict__ g, const float* __restrict__ bb,
    float* outf, ushort* __restrict__ outh, ushort* __restrict__ outl,
    const float* __restrict__ qpos, ushort* __restrict__ q2h, ushort* __restrict__ q2l)
{
    const int wv = threadIdx.x >> 6, lane = threadIdx.x & 63;
    const int row = blockIdx.x * 4 + wv;
    const size_t base = (size_t)row * DM + lane * 4;
    const float4 xv = *(const float4*)(x + base);
    const float4 dv = *(const float4*)(dl + base);
    float v[4] = {xv.x + dv.x, xv.y + dv.y, xv.z + dv.z, xv.w + dv.w};

    float s = v[0] + v[1] + v[2] + v[3];
#pragma unroll
    for (int m = 32; m; m >>= 1) s += __shfl_xor(s, m, 64);
    const float mean = s * (1.f / 256.f);
    float sq = 0.f;
#pragma unroll
    for (int j = 0; j < 4; ++j) { float dd = v[j] - mean; sq += dd * dd; }
#pragma unroll
    for (int m = 32; m; m >>= 1) sq += __shfl_xor(sq, m, 64);
    const float rstd = rsqrtf(sq * (1.f / 256.f) + 1e-5f);

    float y[4];
    ushort4 yh, yl;
#pragma unroll
    for (int j = 0; j < 4; ++j) {
        const int col = lane * 4 + j;
        y[j] = (v[j] - mean) * rstd * g[col] + bb[col];
    }
    *(float4*)(outf + base) = make_float4(y[0], y[1], y[2], y[3]);
    split2(y[0], yh.x, yl.x);
    split2(y[1], yh.y, yl.y);
    split2(y[2], yh.z, yl.z);
    split2(y[3], yh.w, yl.w);
    *(ushort4*)(outh + base) = yh;
    *(ushort4*)(outl + base) = yl;
    if (q2h) {
        const float4 qp = *(const float4*)(qpos + base);
        float q2v[4] = {y[0] + qp.x, y[1] + qp.y, y[2] + qp.z, y[3] + qp.w};
        ushort4 qh_, ql_;
        split2(q2v[0], qh_.x, ql_.x);
        split2(q2v[1], qh_.y, ql_.y);
        split2(q2v[2], qh_.z, ql_.z);
        split2(q2v[3], qh_.w, ql_.w);
        *(ushort4*)(q2h + base) = qh_;
        *(ushort4*)(q2l + base) = ql_;
    }
}

// ---------------------------------------------------------------------------
// Fused bbox-head tail + next-layer qpos stage-1. 32 rows/block (grid 150).
// ---------------------------------------------------------------------------
__global__ __launch_bounds__(256) void bbox_fused(
    const ushort* __restrict__ h2h, const ushort* __restrict__ h2l,
    const float* __restrict__ Wb3, const float* __restrict__ bb3,
    const float* __restrict__ rpu, float* __restrict__ refd,
    float* __restrict__ dout, int mode, int writeout,
    const float* __restrict__ Wp1, const float* __restrict__ bp1,
    ushort* __restrict__ t1h, ushort* __restrict__ t1l, int computeT1)
{
    __shared__ float hls[32 * 258];
    __shared__ float wb3s[1024];
    __shared__ float wp1s[4 * 512];
    __shared__ float bp1s[512];
    __shared__ float ref4[32 * 4];

    const int tid = threadIdx.x;
    const int r0 = blockIdx.x * 32;

    if (computeT1) {
        for (int i = tid; i < 2048; i += 256) wp1s[i] = Wp1[i];
        if (tid < 256) { bp1s[tid] = bp1[tid]; bp1s[tid + 256] = bp1[tid + 256]; }
    }
    if (mode == 1) {
        for (int i = tid; i < 1024; i += 256) wb3s[i] = Wb3[i];
        for (int j = tid; j < 1024; j += 256) {
            const int row = j >> 5, seg = (j & 31) * 8;
            const size_t g = (size_t)(r0 + row) * 256 + seg;
            us8 hv = *(const us8*)&h2h[g];
            us8 lv = *(const us8*)&h2l[g];
            float* o = &hls[row * 258 + seg];
#pragma unroll
            for (int x = 0; x < 8; ++x) o[x] = b2f(hv[x]) + b2f(lv[x]);
        }
    }
    __syncthreads();

    if (tid < 128) {
        const int r = tid >> 2, c = tid & 3;
        float v;
        if (mode == 1) {
            float a0 = 0.f, a1 = 0.f, a2 = 0.f, a3 = 0.f;
            const float* hrow = &hls[r * 258];
#pragma unroll 8
            for (int k = 0; k < 256; k += 4) {
                a0 = fmaf(hrow[k + 0], wb3s[(k + 0) * 4 + c], a0);
                a1 = fmaf(hrow[k + 1], wb3s[(k + 1) * 4 + c], a1);
                a2 = fmaf(hrow[k + 2], wb3s[(k + 2) * 4 + c], a2);
                a3 = fmaf(hrow[k + 3], wb3s[(k + 3) * 4 + c], a3);
            }
            const float b3v = (a0 + a1) + (a2 + a3) + bb3[c];
            const float old = refd[(size_t)(r0 + r) * 4 + c];
            const float rc = fminf(fmaxf(old, 0.f), 1.f);
            const float invs = logf(fmaxf(rc, 1e-5f)) - logf(fmaxf(1.f - rc, 1e-5f));
            v = 1.f / (1.f + __expf(-(b3v + invs)));
        } else {
            v = 1.f / (1.f + __expf(-rpu[(size_t)(r0 + r) * 4 + c]));
        }
        refd[(size_t)(r0 + r) * 4 + c] = v;
        if (writeout) dout[(size_t)(r0 + r) * 4 + c] = v;
        ref4[r * 4 + c] = v;
    }
    __syncthreads();

    if (!computeT1) return;
#pragma unroll
    for (int jj = 0; jj < 8; ++jj) {
        const int idx = jj * 2048 + tid * 8;     // 32 rows x 512 cols
        const int row = idx >> 9, nb = idx & 511;
        const float a0 = ref4[row * 4 + 0], a1 = ref4[row * 4 + 1];
        const float a2 = ref4[row * 4 + 2], a3 = ref4[row * 4 + 3];
        us8 hv, lv;
#pragma unroll
        for (int x = 0; x < 8; ++x) {
            const int n = nb + x;
            float t = bp1s[n];
            t = fmaf(a0, wp1s[n], t);
            t = fmaf(a1, wp1s[512 + n], t);
            t = fmaf(a2, wp1s[1024 + n], t);
            t = fmaf(a3, wp1s[1536 + n], t);
            t = fmaxf(t, 0.f);
            ushort hh, ll;
            split2(t, hh, ll);
            hv[x] = hh; lv[x] = ll;
        }
        const size_t gg = (size_t)(r0 + row) * 512 + nb;
        *(us8*)&t1h[gg] = hv;
        *(us8*)&t1l[gg] = lv;
    }
}

// ---------------------------------------------------------------------------
// Host launch
// ---------------------------------------------------------------------------
extern "C" void kernel_launch(void* const* d_in, const int* in_sizes, int n_in,
                              void* d_out, int out_size, void* d_ws, size_t ws_size,
                              hipStream_t stream)
{
    const float* tgt    = (const float*)d_in[0];
    const float* rpu    = (const float*)d_in[1];
    const float* memory = (const float*)d_in[2];
    const float* Wq  = (const float*)d_in[5];  const float* bq  = (const float*)d_in[6];
    const float* Wk  = (const float*)d_in[7];  const float* bk  = (const float*)d_in[8];
    const float* Wv  = (const float*)d_in[9];  const float* bv  = (const float*)d_in[10];
    const float* Wo  = (const float*)d_in[11]; const float* bo  = (const float*)d_in[12];
    const float* ln1g = (const float*)d_in[13]; const float* ln1b = (const float*)d_in[14];
    const float* ln2g = (const float*)d_in[15]; const float* ln2b = (const float*)d_in[16];
    const float* ln3g = (const float*)d_in[17]; const float* ln3b = (const float*)d_in[18];
    const float* Wvp = (const float*)d_in[19]; const float* bvp = (const float*)d_in[20];
    const float* Woff = (const float*)d_in[21]; const float* boff = (const float*)d_in[22];
    const float* Waw = (const float*)d_in[23]; const float* baw = (const float*)d_in[24];
    const float* Wop = (const float*)d_in[25]; const float* bop = (const float*)d_in[26];
    const float* Wff1 = (const float*)d_in[27]; const float* bff1 = (const float*)d_in[28];
    const float* Wff2 = (const float*)d_in[29]; const float* bff2 = (const float*)d_in[30];
    const float* Wb1 = (const float*)d_in[31]; const float* bb1 = (const float*)d_in[32];
    const float* Wb2 = (const float*)d_in[33]; const float* bb2 = (const float*)d_in[34];
    const float* Wb3 = (const float*)d_in[35]; const float* bb3 = (const float*)d_in[36];
    const float* Ws  = (const float*)d_in[37]; const float* bs_ = (const float*)d_in[38];
    const float* Wp1 = (const float*)d_in[39]; const float* bp1 = (const float*)d_in[40];
    const float* Wp2 = (const float*)d_in[41]; const float* bp2 = (const float*)d_in[42];

    size_t off = 0;
    auto alloc = [&](size_t elems, size_t elsz) -> void* {
        void* r = (char*)d_ws + off;
        off += elems * elsz;
        off = (off + 255) & ~(size_t)255;
        return r;
    };
    ushort *wqkh = (ushort*)alloc(6 * 131072, 2);
    ushort *wvh  = (ushort*)alloc(6 * 65536, 2);
    ushort *woh  = (ushort*)alloc(6 * 65536, 2);
    ushort *wvph = (ushort*)alloc(6 * 65536, 2);
    ushort *wfah = (ushort*)alloc(6 * 81920, 2);
    ushort *woph = (ushort*)alloc(6 * 65536, 2);
    ushort *wf1h = (ushort*)alloc(6 * 262144, 2);
    ushort *wf2h = (ushort*)alloc(6 * 262144, 2);
    ushort *wb1h = (ushort*)alloc(6 * 65536, 2);
    ushort *wb2h = (ushort*)alloc(6 * 65536, 2);
    ushort *wsh  = (ushort*)alloc(6 * 20480, 2);
    ushort *wp2h = (ushort*)alloc(131072, 2);
    float  *bqk  = (float*)alloc(6 * 512, 4);
    float  *bfa  = (float*)alloc(6 * 288, 4);

    ushort* mem_bf = (ushort*)alloc((size_t)MEMN * DM, 2);   // 68.8 MB
    ushort* val_bf = (ushort*)alloc((size_t)MEMN * DM, 2);   // 68.8 MB
    float*  out_f  = (float*)alloc(NROW * DM, 4);
    float*  qpos_f = (float*)alloc(NROW * DM, 4);
    float*  tmp_f  = (float*)alloc(NROW * DM, 4);
    float*  refd_f = (float*)alloc(NROW * 4, 4);
    float*  offaw_f = (float*)alloc(NROW * 288, 4);

    ushort* out_h = (ushort*)alloc(NROW * DM, 2);
    ushort* out_l = (ushort*)alloc(NROW * DM, 2);

    // Lifetime-aliased bf16 scratch arena (units of NROW ushorts) — see R3/R4.
    const size_t NN = NROW;
    ushort* scratch = (ushort*)alloc(NN * 2056, 2);
    ushort* q_h  = scratch;
    ushort* q_l  = scratch + NN * 256;
    ushort* vh_h = scratch + NN * 512;
    ushort* att_h = scratch;
    ushort* att_l = scratch + NN * 256;
    ushort* q2_h = scratch + NN * 512;
    ushort* q2_l = scratch + NN * 768;
    ushort* samp_h = scratch;
    ushort* samp_l = scratch + NN * 256;
    ushort* ff_h = scratch;
    ushort* ff_l = scratch + NN * 1024;
    ushort* h1_h = scratch;
    ushort* h1_l = scratch + NN * 256;
    ushort* h2_h = scratch + NN * 512;
    ushort* h2_l = scratch + NN * 768;
    ushort* t1_h = scratch + NN * 1024;
    ushort* t1_l = scratch + NN * 1536;
    ushort* qk_h = scratch + NN * 1024;   // 514*NN needed; t1 dead when written

    if (off > ws_size) return;

    // ---- batched weight transpose (1 dispatch) ----
    {
        TTab tab;
        const float* ss[NTE] = {Wq, Wk, Wv, Wo, Wvp, Woff, Waw, Wop,
                                Wff1, Wff2, Wb1, Wb2, Ws, Wp2};
        ushort* dd[NTE] = {wqkh, wqkh, wvh, woh, wvph, wfah, wfah, woph,
                           wf1h, wf2h, wb1h, wb2h, wsh, wp2h};
        const int KK[NTE]  = {256, 256, 256, 256, 256, 256, 256, 256,
                              256, 1024, 256, 256, 256, 512};
        const int NNe[NTE] = {256, 256, 256, 256, 256, 192, 96, 256,
                              1024, 256, 256, 256, 80, 256};
        const int BB[NTE]  = {6, 6, 6, 6, 6, 6, 6, 6, 6, 6, 6, 6, 6, 1};
        const int DL[NTE]  = {131072, 131072, 65536, 65536, 65536, 81920, 81920,
                              65536, 262144, 262144, 65536, 65536, 20480, 131072};
        const int DR[NTE]  = {0, 256, 0, 0, 0, 0, 192, 0, 0, 0, 0, 0, 0, 0};
        int total = 0;
        for (int e = 0; e < NTE; ++e) {
            tab.s[e] = ss[e]; tab.d[e] = dd[e];
            tab.K[e] = KK[e]; tab.N[e] = NNe[e];
            tab.dls[e] = DL[e]; tab.dr0[e] = DR[e];
            tab.tstart[e] = total;
            total += ((NNe[e] + 31) / 32) * ((KK[e] + 31) / 32) * BB[e];
        }
        tab.tstart[NTE] = total;
        transpose_batch_kernel<<<total, dim3(32, 8), 0, stream>>>(tab);
    }
    concat_both_kernel<<<19, 256, 0, stream>>>(bq, bk, bqk, boff, baw, bfa);
    f2b_kernel<<<(MEMN * DM) / 1024, 256, 0, stream>>>(memory, mem_bf, MEMN * DM);

    hipMemcpyAsync(out_f, tgt, (size_t)NROW * DM * 4, hipMemcpyDeviceToDevice, stream);
    split_kernel<<<(NROW * DM) / 1024, 256, 0, stream>>>(tgt, out_h, out_l, NROW * DM);
    bbox_fused<<<150, 256, 0, stream>>>(nullptr, nullptr, Wb3, bb3, rpu, refd_f,
                                        nullptr, 0, 0, Wp1, bp1, t1_h, t1_l, 1);

    auto GP = [&](const ushort* Ahp, const ushort* Alp, const ushort* BTh,
                  const float* bias, int N, int K, bool relu,
                  float* Cf, ushort* Ch = nullptr, ushort* Cl = nullptr,
                  const float* addsrc = nullptr) {
        dim3 g(NROW / 64, (N + 63) / 64);
        if (relu) gemm_ps<1><<<g, 256, 0, stream>>>(Ahp, Alp, BTh, bias, NROW, N, K,
                                                    Cf, addsrc, Ch, Cl);
        else      gemm_ps<0><<<g, 256, 0, stream>>>(Ahp, Alp, BTh, bias, NROW, N, K,
                                                    Cf, addsrc, Ch, Cl);
    };
    // tiny-tile variant for the low-occupancy call sites (1200 blocks)
    auto GP16 = [&](const ushort* Ahp, const ushort* Alp, const ushort* BTh,
                    const float* bias, int N, int K, bool relu,
                    float* Cf, ushort* Ch = nullptr, ushort* Cl = nullptr,
                    const float* addsrc = nullptr) {
        dim3 g(NROW / 16, (N + 63) / 64);
        if (relu) gemm_ps16<1><<<g, 256, 0, stream>>>(Ahp, Alp, BTh, bias, NROW, N, K,
                                                      Cf, addsrc, Ch, Cl);
        else      gemm_ps16<0><<<g, 256, 0, stream>>>(Ahp, Alp, BTh, bias, NROW, N, K,
                                                      Cf, addsrc, Ch, Cl);
    };

    for (int i = 0; i < NLAYERS; ++i) {
        const ushort* wvp_i = wvph + i * 65536;
        const float*  bvp_i = bvp + i * 256;
        // Wp2 GEMM + val-proj chunk 0 (700 blocks)
        gemm_mix<<<300 + 700, 256, 0, stream>>>(
            t1_h, t1_l, wp2h, bp2, 256, 512, qpos_f, out_f, q_h, q_l,
            300, mem_bf, wvp_i, bvp_i, val_bf, 0);
        // MHA projections: QK (N=512) + V (N=256) in one dispatch
        gemm_qkv<<<dim3(NROW / 64, 12), 256, 0, stream>>>(
            q_h, q_l, out_h, out_l, wqkh + i * 131072, wvh + i * 65536,
            bqk + i * 512, bv + i * 256, qk_h, vh_h);
        mha_mfma_kernel<<<512, 256, 0, stream>>>(qk_h, 512, qk_h + 256, 512,
                                                 vh_h, 256, att_h, att_l);
        // Wo GEMM + val-proj chunk 1
        gemm_mix<<<300 + 700, 256, 0, stream>>>(
            att_h, att_l, woh + i * 65536, bo + i * 256, 256, 256, tmp_f,
            nullptr, nullptr, nullptr,
            300, mem_bf, wvp_i, bvp_i, val_bf, 700);
        addln_kernel<<<1200, 256, 0, stream>>>(out_f, tmp_f, ln1g + i * 256, ln1b + i * 256,
                                               out_f, out_h, out_l, qpos_f, q2_h, q2_l);
        // offaw GEMM + val-proj chunk 2 (completes val_bf before deform)
        gemm_mix<<<375 + 700, 256, 0, stream>>>(
            q2_h, q2_l, wfah + i * 81920, bfa + i * 288, 288, 256, offaw_f,
            nullptr, nullptr, nullptr,
            375, mem_bf, wvp_i, bvp_i, val_bf, 1400);
        deform_kernel<<<1200, 256, 0, stream>>>(val_bf, offaw_f, refd_f, samp_h, samp_l);
        GP16(samp_h, samp_l, woph + i * 65536, bop + i * 256, 256, 256, false, tmp_f);
        addln_kernel<<<1200, 256, 0, stream>>>(out_f, tmp_f, ln2g + i * 256, ln2b + i * 256,
                                               out_f, out_h, out_l, nullptr, nullptr, nullptr);
        // FFN
        GP(out_h, out_l, wf1h + i * 262144, bff1 + i * 1024, 1024, 256, true,
           nullptr, ff_h, ff_l);
        GP16(ff_h, ff_l, wf2h + i * 262144, bff2 + i * 256, 256, 1024, false, tmp_f);
        addln_kernel<<<1200, 256, 0, stream>>>(out_f, tmp_f, ln3g + i * 256, ln3b + i * 256,
                                               out_f, out_h, out_l, nullptr, nullptr, nullptr);
        // bbox head
        GP16(out_h, out_l, wb1h + i * 65536, bb1 + i * 256, 256, 256, true,
             nullptr, h1_h, h1_l);
        GP16(h1_h, h1_l, wb2h + i * 65536, bb2 + i * 256, 256, 256, true,
             nullptr, h2_h, h2_l);
        const int last = (i == NLAYERS - 1);
        bbox_fused<<<150, 256, 0, stream>>>(h2_h, h2_l, Wb3 + i * 1024, bb3 + i * 4,
                                            nullptr, refd_f, (float*)d_out, 1,
                                            last ? 1 : 0, Wp1, bp1, t1_h, t1_l,
                                            last ? 0 : 1);
        if (last) {
            GP16(out_h, out_l, wsh + i * 20480, bs_ + i * 80, 80, 256, false,
                 (float*)d_out + NROW * 4);
        }
    }
}